// Round 4
// baseline (510.789 us; speedup 1.0000x reference)
//
#include <hip/hip_runtime.h>
#include <hip/hip_bf16.h>

#define S 2048
#define D 1024
#define NH 16
#define HD 64
#define NE 65536
#define DH 512
#define SLOTS 128

typedef __attribute__((ext_vector_type(8))) short short8;
typedef __attribute__((ext_vector_type(4))) float f32x4;

#define MFMA16(a, b, c) __builtin_amdgcn_mfma_f32_16x16x32_bf16(a, b, c, 0, 0, 0)

__device__ __forceinline__ unsigned short f2bf(float f) {
    __hip_bfloat16 h = __float2bfloat16(f);
    return *reinterpret_cast<unsigned short*>(&h);
}
__device__ __forceinline__ float bf2f(unsigned short u) {
    unsigned int x = ((unsigned int)u) << 16;
    return *reinterpret_cast<float*>(&x);
}

// ---------------- prep: fp32 -> bf16 conversions ----------------
__global__ __launch_bounds__(256) void k_convert_x(const float* __restrict__ x,
                                                   unsigned short* __restrict__ xb) {
    int i = (blockIdx.x * 256 + threadIdx.x) * 4;
    const float4 v = *reinterpret_cast<const float4*>(x + i);
    xb[i + 0] = f2bf(v.x);
    xb[i + 1] = f2bf(v.y);
    xb[i + 2] = f2bf(v.z);
    xb[i + 3] = f2bf(v.w);
}

// 5 weight slots (2MB bf16 each): 0=Wq 1=Wk 2=Wv 3=Wn1[:, :1024] 4=Wo
__global__ __launch_bounds__(256) void k_convert_w(const float* __restrict__ Wq,
                                                   const float* __restrict__ Wk,
                                                   const float* __restrict__ Wv,
                                                   const float* __restrict__ Wn1,
                                                   const float* __restrict__ Wo,
                                                   unsigned short* __restrict__ wb) {
    int row = blockIdx.x, mat = blockIdx.y, t = threadIdx.x;
    if (mat == 3 && row >= DH) return;
    const float* src;
    long stride = 1024;
    if (mat == 0) src = Wq;
    else if (mat == 1) src = Wk;
    else if (mat == 2) src = Wv;
    else if (mat == 3) { src = Wn1; stride = 1026; }
    else src = Wo;
    const float* r = src + (long)row * stride;
    unsigned short* o = wb + (long)mat * 1048576 + (long)row * 1024;
#pragma unroll
    for (int j = 0; j < 4; j++) o[t * 4 + j] = f2bf(r[t * 4 + j]);
}

// ---------------- stoich CSR build (numpy last-wins dedup) ----------------
__global__ __launch_bounds__(256) void k_scatter_max(const int* __restrict__ ei,
                                                     int* __restrict__ order) {
    int e = blockIdx.x * 256 + threadIdx.x;
    int r = ei[e], c = ei[NE + e];
    atomicMax(&order[r * S + c], e + 1);
}

__global__ __launch_bounds__(256) void k_scatter_csr(const int* __restrict__ ei,
                                                     const float* __restrict__ st,
                                                     const int* __restrict__ order,
                                                     int* __restrict__ rowcnt,
                                                     int* __restrict__ cidx,
                                                     float* __restrict__ cval) {
    int e = blockIdx.x * 256 + threadIdx.x;
    int r = ei[e], c = ei[NE + e];
    if (order[r * S + c] == e + 1) {
        int i = atomicAdd(&rowcnt[r], 1);
        if (i < SLOTS) {
            cidx[r * SLOTS + i] = c;
            cval[r * SLOTS + i] = st[e];
        }
    }
}

// ---------------- fused QKV + hidden GEMM ----------------
// z=0: Q -> [h][s][hd]  z=1: K -> [h][s][hd]  z=2: V -> [h][s][hd]
// z=3: hidden (N=512) -> fp32 [s][512]
__global__ __launch_bounds__(256) void k_gemm_qkvh(const unsigned short* __restrict__ xb,
                                                   const unsigned short* __restrict__ wb,
                                                   const float* __restrict__ bq,
                                                   const float* __restrict__ bk,
                                                   const float* __restrict__ bv,
                                                   const float* __restrict__ bn1,
                                                   unsigned short* __restrict__ qout,
                                                   unsigned short* __restrict__ kout,
                                                   unsigned short* __restrict__ vout,
                                                   float* __restrict__ hidden) {
    const int z = blockIdx.z;
    if (z == 3 && blockIdx.y >= 8) return;
    const int tid = threadIdx.x, w = tid >> 6, lane = tid & 63;
    const int l15 = lane & 15, lhi = lane >> 4;
    const int m0 = blockIdx.x * 64 + w * 16;
    const int n0 = blockIdx.y * 64;
    const unsigned short* W = wb + (long)z * 1048576;
    f32x4 acc[4];
#pragma unroll
    for (int t = 0; t < 4; t++) acc[t] = (f32x4){0.f, 0.f, 0.f, 0.f};
    const unsigned short* ap0 = xb + (long)(m0 + l15) * 1024 + lhi * 8;
    const unsigned short* bp0 = W + (long)(n0 + l15) * 1024 + lhi * 8;
    for (int kc = 0; kc < 32; kc++) {
        short8 a = *reinterpret_cast<const short8*>(ap0 + kc * 32);
#pragma unroll
        for (int t = 0; t < 4; t++) {
            short8 b = *reinterpret_cast<const short8*>(bp0 + (long)t * 16 * 1024 + kc * 32);
            acc[t] = MFMA16(a, b, acc[t]);
        }
    }
    const float* bias = (z == 0) ? bq : ((z == 1) ? bk : ((z == 2) ? bv : bn1));
#pragma unroll
    for (int t = 0; t < 4; t++) {
        int n = n0 + t * 16 + l15;
        float bb = bias[n];
#pragma unroll
        for (int r = 0; r < 4; r++) {
            int m = m0 + lhi * 4 + r;
            float v = acc[t][r] + bb;
            if (z == 3) {
                hidden[(long)m * DH + n] = v;
            } else {
                unsigned short bits = f2bf(v);
                int hh = n >> 6, hd = n & 63;
                unsigned short* dst = (z == 0) ? qout : ((z == 1) ? kout : vout);
                dst[(long)hh * S * HD + (long)m * HD + hd] = bits;
            }
        }
    }
}

// ---------------- node-type MLP tail -> ntwT [h][s] ----------------
__global__ __launch_bounds__(256) void k_ntw(const float* __restrict__ hidden,
                                             const float* __restrict__ Wn1,
                                             const float* __restrict__ nt,
                                             const float* __restrict__ Wn2,
                                             const float* __restrict__ bn2,
                                             float* __restrict__ ntwT) {
    int s = blockIdx.x, tid = threadIdx.x;
    __shared__ float rh[DH];
    __shared__ float part[16][17];
    float nt0 = nt[s * 2 + 0], nt1 = nt[s * 2 + 1];
    for (int j = tid; j < DH; j += 256) {
        float v = hidden[(long)s * DH + j] + nt0 * Wn1[(long)j * 1026 + 1024]
                + nt1 * Wn1[(long)j * 1026 + 1025];
        rh[j] = fmaxf(v, 0.f);
    }
    __syncthreads();
    {
        int hh = tid & 15, ch = tid >> 4;
        float p = 0.f;
#pragma unroll
        for (int j = 0; j < 32; j++) p += rh[ch * 32 + j] * Wn2[hh * DH + ch * 32 + j];
        part[ch][hh] = p;
    }
    __syncthreads();
    if (tid < 16) {
        float l = bn2[tid];
#pragma unroll
        for (int c = 0; c < 16; c++) l += part[c][tid];
        float mx = l;
#pragma unroll
        for (int m = 1; m < 16; m <<= 1) mx = fmaxf(mx, __shfl_xor(mx, m));
        float e = __expf(l - mx);
        float sum = e;
#pragma unroll
        for (int m = 1; m < 16; m <<= 1) sum += __shfl_xor(sum, m);
        ntwT[tid * S + s] = e / sum;
    }
}

// ---------------- V column sums per head (with bias, included via V) ----------------
__global__ __launch_bounds__(256) void k_vsum(const unsigned short* __restrict__ vb,
                                              float* __restrict__ vsum) {
    int h = blockIdx.x, tid = threadIdx.x;
    int lane = tid & 63, grp = tid >> 6;
    __shared__ float p[4][64];
    float acc = 0.f;
    for (int r = grp; r < S; r += 4) acc += bf2f(vb[((long)h * S + r) * HD + lane]);
    p[grp][lane] = acc;
    __syncthreads();
    if (tid < 64) vsum[h * HD + tid] = p[0][tid] + p[1][tid] + p[2][tid] + p[3][tid];
}

// ---------------- sparse attention ----------------
// scores = (QK^T/8 * ntw[k,h]) * mask, and mask has only ~32 nz per row -> all
// zero-mask entries share score 0. Per (h,q): gm = max(0, max_nz), Z = sum_nz
// exp(s-gm) + (2048-nnz)*exp(-gm); attn row = p0 = exp(-gm)/Z everywhere except
// nz positions; PV = p0*Vsum + sum_nz (p_i - p0) * V[c_i].
__global__ __launch_bounds__(256, 8) void k_sattn(const unsigned short* __restrict__ qb,
                                                  const unsigned short* __restrict__ kb,
                                                  const unsigned short* __restrict__ vb,
                                                  const float* __restrict__ ntwT,
                                                  const int* __restrict__ rowcnt,
                                                  const int* __restrict__ cidx,
                                                  const float* __restrict__ cval,
                                                  const float* __restrict__ vsum,
                                                  float* __restrict__ attn_out,
                                                  unsigned short* __restrict__ pv_out) {
    __shared__ float s_sc[SLOTS];
    __shared__ float s_pd[SLOTS];
    __shared__ int s_c[SLOTS];
    __shared__ float s_pv[4][64];
    __shared__ float redv[4];

    const int tid = threadIdx.x, w = tid >> 6, lane = tid & 63;
    int b = (int)blockIdx.x;
    b = (b & 7) * 4096 + (b >> 3);  // XCD swizzle: 4096 consecutive (h,q) per XCD
    const int h = b >> 11, q = b & 2047;
    const int nnz_raw = rowcnt[q];
    const int nnz = nnz_raw < SLOTS ? nnz_raw : SLOTS;

    const float qvf = bf2f(qb[((long)h * S + q) * HD + lane]);

    // phase 1: fp32 dots at nz positions (wave-parallel over nz, lane-parallel over dim)
    for (int i = w; i < nnz; i += 4) {
        int c = cidx[q * SLOTS + i];
        float p = qvf * bf2f(kb[((long)h * S + c) * HD + lane]);
#pragma unroll
        for (int off = 32; off >= 1; off >>= 1) p += __shfl_xor(p, off);
        if (lane == 0) {
            s_sc[i] = p * 0.125f * ntwT[(long)h * S + c] * cval[q * SLOTS + i];
            s_c[i] = c;
        }
    }
    __syncthreads();

    // phase 2: block softmax stats
    float v = (tid < nnz) ? s_sc[tid] : -3.0e38f;
    float mx = v;
#pragma unroll
    for (int off = 32; off >= 1; off >>= 1) mx = fmaxf(mx, __shfl_xor(mx, off));
    if (lane == 0) redv[w] = mx;
    __syncthreads();
    float gm = fmaxf(fmaxf(redv[0], redv[1]), fmaxf(redv[2], redv[3]));
    gm = fmaxf(gm, 0.f);
    __syncthreads();
    float e = (tid < nnz) ? __expf(v - gm) : 0.f;
    float sm = e;
#pragma unroll
    for (int off = 32; off >= 1; off >>= 1) sm += __shfl_xor(sm, off);
    if (lane == 0) redv[w] = sm;
    __syncthreads();
    const float Z = redv[0] + redv[1] + redv[2] + redv[3]
                  + (float)(S - nnz) * __expf(-gm);
    const float inv = 1.0f / Z;
    const float p0 = __expf(-gm) * inv;
    if (tid < nnz) {
        float p = e * inv;
        s_sc[tid] = p;
        s_pd[tid] = p - p0;
    }
    __syncthreads();

    // phase 3: fill attn row with p0, then scatter nz values
    float* arow = attn_out + ((long)h * S + q) * S;
    float4* a4 = reinterpret_cast<float4*>(arow);
    float4 f4 = {p0, p0, p0, p0};
    a4[tid] = f4;
    a4[256 + tid] = f4;
    __syncthreads();
    if (tid < nnz) arow[s_c[tid]] = s_sc[tid];

    // phase 4: sparse PV
    float pvacc = 0.f;
    for (int i = w; i < nnz; i += 4) {
        pvacc += s_pd[i] * bf2f(vb[((long)h * S + s_c[i]) * HD + lane]);
    }
    s_pv[w][lane] = pvacc;
    __syncthreads();
    if (w == 0) {
        float tot = s_pv[0][lane] + s_pv[1][lane] + s_pv[2][lane] + s_pv[3][lane]
                  + p0 * vsum[h * HD + lane];
        pv_out[(long)q * D + h * HD + lane] = f2bf(tot);
    }
}

// ---------------- out projection GEMM (bf16 A) ----------------
__global__ __launch_bounds__(256) void k_gemm_out(const unsigned short* __restrict__ A,
                                                  const unsigned short* __restrict__ wo,
                                                  const float* __restrict__ bo,
                                                  float* __restrict__ proj) {
    const int tid = threadIdx.x, w = tid >> 6, lane = tid & 63;
    const int l15 = lane & 15, lhi = lane >> 4;
    const int m0 = blockIdx.x * 64 + w * 16;
    const int n0 = blockIdx.y * 64;
    f32x4 acc[4];
#pragma unroll
    for (int t = 0; t < 4; t++) acc[t] = (f32x4){0.f, 0.f, 0.f, 0.f};
    const unsigned short* ap0 = A + (long)(m0 + l15) * 1024 + lhi * 8;
    const unsigned short* bp0 = wo + (long)(n0 + l15) * 1024 + lhi * 8;
    for (int kc = 0; kc < 32; kc++) {
        short8 a = *reinterpret_cast<const short8*>(ap0 + kc * 32);
#pragma unroll
        for (int t = 0; t < 4; t++) {
            short8 b = *reinterpret_cast<const short8*>(bp0 + (long)t * 16 * 1024 + kc * 32);
            acc[t] = MFMA16(a, b, acc[t]);
        }
    }
#pragma unroll
    for (int t = 0; t < 4; t++) {
        int n = n0 + t * 16 + l15;
        float bb = bo[n];
#pragma unroll
        for (int r = 0; r < 4; r++) {
            int m = m0 + lhi * 4 + r;
            proj[(long)m * 1024 + n] = acc[t][r] + bb;
        }
    }
}

// ---------------- residual + LayerNorm ----------------
__global__ __launch_bounds__(256) void k_ln(const float* __restrict__ x,
                                            const float* __restrict__ proj,
                                            const float* __restrict__ g,
                                            const float* __restrict__ bta,
                                            float* __restrict__ y) {
    int s = blockIdx.x, tid = threadIdx.x;
    int w = tid >> 6, lane = tid & 63;
    __shared__ float red[8];
    float4 xv = reinterpret_cast<const float4*>(x + (long)s * 1024)[tid];
    float4 pv = reinterpret_cast<const float4*>(proj + (long)s * 1024)[tid];
    float t0 = xv.x + pv.x, t1 = xv.y + pv.y, t2 = xv.z + pv.z, t3 = xv.w + pv.w;
    float lsum = t0 + t1 + t2 + t3;
#pragma unroll
    for (int m = 32; m >= 1; m >>= 1) lsum += __shfl_xor(lsum, m);
    if (lane == 0) red[w] = lsum;
    __syncthreads();
    float mean = (red[0] + red[1] + red[2] + red[3]) * (1.0f / 1024.f);
    float d0 = t0 - mean, d1 = t1 - mean, d2 = t2 - mean, d3 = t3 - mean;
    float lvar = d0 * d0 + d1 * d1 + d2 * d2 + d3 * d3;
#pragma unroll
    for (int m = 32; m >= 1; m >>= 1) lvar += __shfl_xor(lvar, m);
    if (lane == 0) red[4 + w] = lvar;
    __syncthreads();
    float var = (red[4] + red[5] + red[6] + red[7]) * (1.0f / 1024.f);
    float rstd = rsqrtf(var + 1e-5f);
    float4 gv = reinterpret_cast<const float4*>(g)[tid];
    float4 bv = reinterpret_cast<const float4*>(bta)[tid];
    float4 out;
    out.x = d0 * rstd * gv.x + bv.x;
    out.y = d1 * rstd * gv.y + bv.y;
    out.z = d2 * rstd * gv.z + bv.z;
    out.w = d3 * rstd * gv.w + bv.w;
    reinterpret_cast<float4*>(y + (long)s * 1024)[tid] = out;
}

extern "C" void kernel_launch(void* const* d_in, const int* in_sizes, int n_in,
                              void* d_out, int out_size, void* d_ws, size_t ws_size,
                              hipStream_t stream) {
    const float* x = (const float*)d_in[0];
    const float* node_types = (const float*)d_in[1];
    const float* stoich = (const float*)d_in[2];
    const float* Wq = (const float*)d_in[3];
    const float* bq = (const float*)d_in[4];
    const float* Wk = (const float*)d_in[5];
    const float* bk = (const float*)d_in[6];
    const float* Wv = (const float*)d_in[7];
    const float* bv = (const float*)d_in[8];
    const float* Wo = (const float*)d_in[9];
    const float* bo = (const float*)d_in[10];
    const float* Wn1 = (const float*)d_in[11];
    const float* bn1 = (const float*)d_in[12];
    const float* Wn2 = (const float*)d_in[13];
    const float* bn2 = (const float*)d_in[14];
    const float* ln_g = (const float*)d_in[15];
    const float* ln_b = (const float*)d_in[16];
    const int* ei = (const int*)d_in[17];

    char* ws = (char*)d_ws;
    unsigned short* x_bf = (unsigned short*)(ws);                 // 0..4M
    unsigned short* q_bf = (unsigned short*)(ws + (4l << 20));    // 4..8M  [h][s][hd]
    unsigned short* k_bf = (unsigned short*)(ws + (8l << 20));    // 8..12M [h][s][hd]
    unsigned short* v_bf = (unsigned short*)(ws + (12l << 20));   // 12..16M [h][s][hd]
    unsigned short* w_bf = (unsigned short*)(ws + (16l << 20));   // 16..26M 5 slots
    float* hidden = (float*)(ws + (26l << 20));                   // 26..30M
    float* ntwT = (float*)(ws + (30l << 20));                     // 30M +128KB [h][s]
    float* vsum = (float*)(ws + (30l << 20) + (256l << 10));      // 4KB
    int* rowcnt = (int*)(ws + (30l << 20) + (512l << 10));        // 8KB
    int* cidx = (int*)(ws + (31l << 20));                         // 31..32M
    float* cval = (float*)(ws + (32l << 20));                     // 32..33M
    int* order = (int*)(ws + (33l << 20));                        // 33..49M
    unsigned short* pvb = (unsigned short*)(ws + (49l << 20));    // 49..53M bf16 [s][1024]
    float* proj = (float*)(ws + (53l << 20));                     // 53..61M

    float* y_out = (float*)d_out;
    float* attn_out = (float*)d_out + (long)S * D;  // 2097152

    hipMemsetAsync(order, 0, 16l << 20, stream);
    hipMemsetAsync(rowcnt, 0, 8l << 10, stream);
    k_convert_x<<<2048, 256, 0, stream>>>(x, x_bf);
    k_convert_w<<<dim3(1024, 5), 256, 0, stream>>>(Wq, Wk, Wv, Wn1, Wo, w_bf);
    k_scatter_max<<<256, 256, 0, stream>>>(ei, order);
    k_scatter_csr<<<256, 256, 0, stream>>>(ei, stoich, order, rowcnt, cidx, cval);
    k_gemm_qkvh<<<dim3(32, 16, 4), 256, 0, stream>>>(x_bf, w_bf, bq, bk, bv, bn1,
                                                     q_bf, k_bf, v_bf, hidden);
    k_ntw<<<2048, 256, 0, stream>>>(hidden, Wn1, node_types, Wn2, bn2, ntwT);
    k_vsum<<<16, 256, 0, stream>>>(v_bf, vsum);
    k_sattn<<<32768, 256, 0, stream>>>(q_bf, k_bf, v_bf, ntwT, rowcnt, cidx, cval,
                                       vsum, attn_out, pvb);
    k_gemm_out<<<dim3(32, 16), 256, 0, stream>>>(pvb, w_bf + 4l * 1048576, bo, proj);
    k_ln<<<2048, 256, 0, stream>>>(x, proj, ln_g, ln_b, y_out);
}

// Round 5
// 318.691 us; speedup vs baseline: 1.6028x; 1.6028x over previous
//
#include <hip/hip_runtime.h>
#include <hip/hip_bf16.h>

#define S 2048
#define D 1024
#define NH 16
#define HD 64
#define NE 65536
#define DH 512
#define SLOTS 128

typedef __attribute__((ext_vector_type(8))) short short8;
typedef __attribute__((ext_vector_type(4))) float f32x4;

#define MFMA16(a, b, c) __builtin_amdgcn_mfma_f32_16x16x32_bf16(a, b, c, 0, 0, 0)

__device__ __forceinline__ unsigned short f2bf(float f) {
    __hip_bfloat16 h = __float2bfloat16(f);
    return *reinterpret_cast<unsigned short*>(&h);
}
__device__ __forceinline__ float bf2f(unsigned short u) {
    unsigned int x = ((unsigned int)u) << 16;
    return *reinterpret_cast<float*>(&x);
}

// ---------------- prep: fp32 -> bf16 conversions ----------------
__global__ __launch_bounds__(256) void k_convert_x(const float* __restrict__ x,
                                                   unsigned short* __restrict__ xb) {
    int i = (blockIdx.x * 256 + threadIdx.x) * 4;
    const float4 v = *reinterpret_cast<const float4*>(x + i);
    xb[i + 0] = f2bf(v.x);
    xb[i + 1] = f2bf(v.y);
    xb[i + 2] = f2bf(v.z);
    xb[i + 3] = f2bf(v.w);
}

// 5 weight slots (2MB bf16 each): 0=Wq 1=Wk 2=Wv 3=Wn1[:, :1024] 4=Wo
__global__ __launch_bounds__(256) void k_convert_w(const float* __restrict__ Wq,
                                                   const float* __restrict__ Wk,
                                                   const float* __restrict__ Wv,
                                                   const float* __restrict__ Wn1,
                                                   const float* __restrict__ Wo,
                                                   unsigned short* __restrict__ wb) {
    int row = blockIdx.x, mat = blockIdx.y, t = threadIdx.x;
    if (mat == 3 && row >= DH) return;
    const float* src;
    long stride = 1024;
    if (mat == 0) src = Wq;
    else if (mat == 1) src = Wk;
    else if (mat == 2) src = Wv;
    else if (mat == 3) { src = Wn1; stride = 1026; }
    else src = Wo;
    const float* r = src + (long)row * stride;
    unsigned short* o = wb + (long)mat * 1048576 + (long)row * 1024;
#pragma unroll
    for (int j = 0; j < 4; j++) o[t * 4 + j] = f2bf(r[t * 4 + j]);
}

// ---------------- stoich CSR build (numpy last-wins dedup) ----------------
__global__ __launch_bounds__(256) void k_scatter_max(const int* __restrict__ ei,
                                                     int* __restrict__ order) {
    int e = blockIdx.x * 256 + threadIdx.x;
    int r = ei[e], c = ei[NE + e];
    atomicMax(&order[r * S + c], e + 1);
}

__global__ __launch_bounds__(256) void k_scatter_csr(const int* __restrict__ ei,
                                                     const float* __restrict__ st,
                                                     const int* __restrict__ order,
                                                     int* __restrict__ rowcnt,
                                                     int* __restrict__ cidx,
                                                     float* __restrict__ cval) {
    int e = blockIdx.x * 256 + threadIdx.x;
    int r = ei[e], c = ei[NE + e];
    if (order[r * S + c] == e + 1) {
        int i = atomicAdd(&rowcnt[r], 1);
        if (i < SLOTS) {
            cidx[r * SLOTS + i] = c;
            cval[r * SLOTS + i] = st[e];
        }
    }
}

// ---------------- fused QKV + hidden GEMM ----------------
__global__ __launch_bounds__(256) void k_gemm_qkvh(const unsigned short* __restrict__ xb,
                                                   const unsigned short* __restrict__ wb,
                                                   const float* __restrict__ bq,
                                                   const float* __restrict__ bk,
                                                   const float* __restrict__ bv,
                                                   const float* __restrict__ bn1,
                                                   unsigned short* __restrict__ qout,
                                                   unsigned short* __restrict__ kout,
                                                   unsigned short* __restrict__ vout,
                                                   float* __restrict__ hidden) {
    const int z = blockIdx.z;
    if (z == 3 && blockIdx.y >= 8) return;
    const int tid = threadIdx.x, w = tid >> 6, lane = tid & 63;
    const int l15 = lane & 15, lhi = lane >> 4;
    const int m0 = blockIdx.x * 64 + w * 16;
    const int n0 = blockIdx.y * 64;
    const unsigned short* W = wb + (long)z * 1048576;
    f32x4 acc[4];
#pragma unroll
    for (int t = 0; t < 4; t++) acc[t] = (f32x4){0.f, 0.f, 0.f, 0.f};
    const unsigned short* ap0 = xb + (long)(m0 + l15) * 1024 + lhi * 8;
    const unsigned short* bp0 = W + (long)(n0 + l15) * 1024 + lhi * 8;
    for (int kc = 0; kc < 32; kc++) {
        short8 a = *reinterpret_cast<const short8*>(ap0 + kc * 32);
#pragma unroll
        for (int t = 0; t < 4; t++) {
            short8 b = *reinterpret_cast<const short8*>(bp0 + (long)t * 16 * 1024 + kc * 32);
            acc[t] = MFMA16(a, b, acc[t]);
        }
    }
    const float* bias = (z == 0) ? bq : ((z == 1) ? bk : ((z == 2) ? bv : bn1));
#pragma unroll
    for (int t = 0; t < 4; t++) {
        int n = n0 + t * 16 + l15;
        float bb = bias[n];
#pragma unroll
        for (int r = 0; r < 4; r++) {
            int m = m0 + lhi * 4 + r;
            float v = acc[t][r] + bb;
            if (z == 3) {
                hidden[(long)m * DH + n] = v;
            } else {
                unsigned short bits = f2bf(v);
                int hh = n >> 6, hd = n & 63;
                unsigned short* dst = (z == 0) ? qout : ((z == 1) ? kout : vout);
                dst[(long)hh * S * HD + (long)m * HD + hd] = bits;
            }
        }
    }
}

// ---------------- node-type MLP tail -> ntwT [h][s] ----------------
__global__ __launch_bounds__(256) void k_ntw(const float* __restrict__ hidden,
                                             const float* __restrict__ Wn1,
                                             const float* __restrict__ nt,
                                             const float* __restrict__ Wn2,
                                             const float* __restrict__ bn2,
                                             float* __restrict__ ntwT) {
    int s = blockIdx.x, tid = threadIdx.x;
    __shared__ float rh[DH];
    __shared__ float part[16][17];
    float nt0 = nt[s * 2 + 0], nt1 = nt[s * 2 + 1];
    for (int j = tid; j < DH; j += 256) {
        float v = hidden[(long)s * DH + j] + nt0 * Wn1[(long)j * 1026 + 1024]
                + nt1 * Wn1[(long)j * 1026 + 1025];
        rh[j] = fmaxf(v, 0.f);
    }
    __syncthreads();
    {
        int hh = tid & 15, ch = tid >> 4;
        float p = 0.f;
#pragma unroll
        for (int j = 0; j < 32; j++) p += rh[ch * 32 + j] * Wn2[hh * DH + ch * 32 + j];
        part[ch][hh] = p;
    }
    __syncthreads();
    if (tid < 16) {
        float l = bn2[tid];
#pragma unroll
        for (int c = 0; c < 16; c++) l += part[c][tid];
        float mx = l;
#pragma unroll
        for (int m = 1; m < 16; m <<= 1) mx = fmaxf(mx, __shfl_xor(mx, m));
        float e = __expf(l - mx);
        float sum = e;
#pragma unroll
        for (int m = 1; m < 16; m <<= 1) sum += __shfl_xor(sum, m);
        ntwT[tid * S + s] = e / sum;
    }
}

// ---------------- V column sums: 128-block partials + merge ----------------
__global__ __launch_bounds__(256) void k_vsum_part(const unsigned short* __restrict__ vb,
                                                   float* __restrict__ vsump) {
    int h = blockIdx.x, j = blockIdx.y, tid = threadIdx.x;
    int w = tid >> 6, lane = tid & 63;
    __shared__ float p[4][64];
    float acc = 0.f;
    int r0 = j * 256 + w * 64;
    for (int k = 0; k < 64; k++)
        acc += bf2f(vb[((long)h * S + r0 + k) * HD + lane]);
    p[w][lane] = acc;
    __syncthreads();
    if (tid < 64) vsump[(h * 8 + j) * 64 + tid] = p[0][tid] + p[1][tid] + p[2][tid] + p[3][tid];
}

__global__ __launch_bounds__(1024) void k_vsum_merge(const float* __restrict__ vsump,
                                                     float* __restrict__ vsumf) {
    int t = threadIdx.x;  // t = h*64+d
    int h = t >> 6, d = t & 63;
    float a = 0.f;
#pragma unroll
    for (int j = 0; j < 8; j++) a += vsump[(h * 8 + j) * 64 + d];
    vsumf[t] = a;
}

// ---------------- sparse attention compute: one WAVE per (h,q) row ----------------
// Lanes as (i_loc = lane&15 over nz, dpart = lane>>4 over dim quarters).
// 16 dots per chunk via 16 FMA + 2 shfl. Two-pass softmax over <=8 register
// chunks (static unroll). Outputs p0[r], pvals[r][i], and PV (bf16).
__global__ __launch_bounds__(256, 8) void k_sparse(const unsigned short* __restrict__ qb,
                                                   const unsigned short* __restrict__ kb,
                                                   const unsigned short* __restrict__ vb,
                                                   const float* __restrict__ ntwT,
                                                   const int* __restrict__ rowcnt,
                                                   const int* __restrict__ cidx,
                                                   const float* __restrict__ cval,
                                                   const float* __restrict__ vsumf,
                                                   float* __restrict__ p0arr,
                                                   float* __restrict__ pvals,
                                                   unsigned short* __restrict__ pv_out) {
    __shared__ int c_lds[4][SLOTS];
    __shared__ float pd_lds[4][SLOTS];
    const int tid = threadIdx.x, w = tid >> 6, lane = tid & 63;
    int b = (int)blockIdx.x;
    b = (b & 7) * 1024 + (b >> 3);  // XCD swizzle: 2 heads per XCD (K L2-resident)
    const int r = b * 4 + w;
    const int h = r >> 11, q = r & 2047;
    const int i_loc = lane & 15, dpart = lane >> 4;
    const int nnz_raw = rowcnt[q];
    const int nnz = nnz_raw < SLOTS ? nnz_raw : SLOTS;
    const int chunks = (nnz + 15) >> 4;

    // q fragment: 16 dims (this dpart's quarter) as floats
    float qf[16];
    {
        const unsigned short* qp = qb + ((long)h * S + q) * HD + dpart * 16;
        short8 q0 = *reinterpret_cast<const short8*>(qp);
        short8 q1 = *reinterpret_cast<const short8*>(qp + 8);
#pragma unroll
        for (int j = 0; j < 8; j++) {
            qf[j] = bf2f((unsigned short)q0[j]);
            qf[8 + j] = bf2f((unsigned short)q1[j]);
        }
    }

    float s_reg[8];
    int c_reg[8];
#pragma unroll
    for (int c8 = 0; c8 < 8; c8++) {
        s_reg[c8] = -3.0e38f;
        c_reg[c8] = 0;
        if (c8 < chunks) {
            int i = c8 * 16 + i_loc;
            bool valid = i < nnz;
            int idx = q * SLOTS + (valid ? i : 0);
            int c = cidx[idx];
            float vv = cval[idx];
            const unsigned short* kp = kb + ((long)h * S + c) * HD + dpart * 16;
            short8 k0 = *reinterpret_cast<const short8*>(kp);
            short8 k1 = *reinterpret_cast<const short8*>(kp + 8);
            float dot = 0.f;
#pragma unroll
            for (int j = 0; j < 8; j++) {
                dot += qf[j] * bf2f((unsigned short)k0[j]);
                dot += qf[8 + j] * bf2f((unsigned short)k1[j]);
            }
            dot += __shfl_xor(dot, 16);
            dot += __shfl_xor(dot, 32);
            if (valid) {
                s_reg[c8] = dot * 0.125f * ntwT[(long)h * S + c] * vv;
                c_reg[c8] = c;
            }
        }
    }

    // row max (values duplicated across dpart; reduce over i_loc lanes only)
    float m = s_reg[0];
#pragma unroll
    for (int c8 = 1; c8 < 8; c8++) m = fmaxf(m, s_reg[c8]);
    m = fmaxf(m, __shfl_xor(m, 1));
    m = fmaxf(m, __shfl_xor(m, 2));
    m = fmaxf(m, __shfl_xor(m, 4));
    m = fmaxf(m, __shfl_xor(m, 8));
    const float gm = fmaxf(m, 0.f);

    float e_reg[8];
    float zs = 0.f;
#pragma unroll
    for (int c8 = 0; c8 < 8; c8++) {
        e_reg[c8] = __expf(s_reg[c8] - gm);  // invalid -> exp(-inf) = 0
        zs += e_reg[c8];
    }
    zs += __shfl_xor(zs, 1);
    zs += __shfl_xor(zs, 2);
    zs += __shfl_xor(zs, 4);
    zs += __shfl_xor(zs, 8);
    const float e0 = __expf(-gm);
    const float Z = zs + (float)(S - nnz) * e0;
    const float inv = 1.0f / Z;
    const float p0 = e0 * inv;

    if (lane == 0) p0arr[r] = p0;
    if (dpart == 0) {
#pragma unroll
        for (int c8 = 0; c8 < 8; c8++) {
            int i = c8 * 16 + i_loc;
            if (c8 < chunks && i < nnz) {
                float p = e_reg[c8] * inv;
                pvals[(long)r * SLOTS + i] = p;
                c_lds[w][i] = c_reg[c8];
                pd_lds[w][i] = p - p0;
            }
        }
    }
    asm volatile("" ::: "memory");  // order LDS writes before reads (same-wave, HW in-order DS)

    // PV: lanes = output dim d; nz coefficients broadcast from LDS
    float vacc = 0.f;
    for (int i = 0; i < nnz; i++) {
        int c = c_lds[w][i];
        float pd = pd_lds[w][i];
        vacc += pd * bf2f(vb[((long)h * S + c) * HD + lane]);
    }
    vacc += p0 * vsumf[h * HD + lane];
    pv_out[(long)q * D + h * HD + lane] = f2bf(vacc);
}

// ---------------- attn row fill + nz scatter: one WAVE per row, streaming ----------------
__global__ __launch_bounds__(256, 8) void k_fill(const float* __restrict__ p0arr,
                                                 const float* __restrict__ pvals,
                                                 const int* __restrict__ cidx,
                                                 const int* __restrict__ rowcnt,
                                                 float* __restrict__ attn_out) {
    const int tid = threadIdx.x, w = tid >> 6, lane = tid & 63;
    const int r = (int)blockIdx.x * 4 + w;
    const int q = r & 2047;
    const int nnz_raw = rowcnt[q];
    const int nnz = nnz_raw < SLOTS ? nnz_raw : SLOTS;
    const float p0 = p0arr[r];

    // prefetch scatter data
    int c0 = -1, c1 = -1;
    float v0 = 0.f, v1 = 0.f;
    if (lane < nnz) {
        c0 = cidx[q * SLOTS + lane];
        v0 = pvals[(long)r * SLOTS + lane];
    }
    if (lane + 64 < nnz) {
        c1 = cidx[q * SLOTS + lane + 64];
        v1 = pvals[(long)r * SLOTS + lane + 64];
    }

    float* arow = attn_out + (long)r * S;
    float4* a4 = reinterpret_cast<float4*>(arow) + lane;
    const float4 f4 = {p0, p0, p0, p0};
#pragma unroll
    for (int u = 0; u < 8; u++) a4[u * 64] = f4;
    __threadfence_block();  // drain fill stores before same-address scatter
    if (c0 >= 0) arow[c0] = v0;
    if (c1 >= 0) arow[c1] = v1;
}

// ---------------- out projection GEMM (bf16 A) ----------------
__global__ __launch_bounds__(256) void k_gemm_out(const unsigned short* __restrict__ A,
                                                  const unsigned short* __restrict__ wo,
                                                  const float* __restrict__ bo,
                                                  float* __restrict__ proj) {
    const int tid = threadIdx.x, w = tid >> 6, lane = tid & 63;
    const int l15 = lane & 15, lhi = lane >> 4;
    const int m0 = blockIdx.x * 64 + w * 16;
    const int n0 = blockIdx.y * 64;
    f32x4 acc[4];
#pragma unroll
    for (int t = 0; t < 4; t++) acc[t] = (f32x4){0.f, 0.f, 0.f, 0.f};
    const unsigned short* ap0 = A + (long)(m0 + l15) * 1024 + lhi * 8;
    const unsigned short* bp0 = wo + (long)(n0 + l15) * 1024 + lhi * 8;
    for (int kc = 0; kc < 32; kc++) {
        short8 a = *reinterpret_cast<const short8*>(ap0 + kc * 32);
#pragma unroll
        for (int t = 0; t < 4; t++) {
            short8 b = *reinterpret_cast<const short8*>(bp0 + (long)t * 16 * 1024 + kc * 32);
            acc[t] = MFMA16(a, b, acc[t]);
        }
    }
#pragma unroll
    for (int t = 0; t < 4; t++) {
        int n = n0 + t * 16 + l15;
        float bb = bo[n];
#pragma unroll
        for (int r = 0; r < 4; r++) {
            int m = m0 + lhi * 4 + r;
            proj[(long)m * 1024 + n] = acc[t][r] + bb;
        }
    }
}

// ---------------- residual + LayerNorm ----------------
__global__ __launch_bounds__(256) void k_ln(const float* __restrict__ x,
                                            const float* __restrict__ proj,
                                            const float* __restrict__ g,
                                            const float* __restrict__ bta,
                                            float* __restrict__ y) {
    int s = blockIdx.x, tid = threadIdx.x;
    int w = tid >> 6, lane = tid & 63;
    __shared__ float red[8];
    float4 xv = reinterpret_cast<const float4*>(x + (long)s * 1024)[tid];
    float4 pv = reinterpret_cast<const float4*>(proj + (long)s * 1024)[tid];
    float t0 = xv.x + pv.x, t1 = xv.y + pv.y, t2 = xv.z + pv.z, t3 = xv.w + pv.w;
    float lsum = t0 + t1 + t2 + t3;
#pragma unroll
    for (int m = 32; m >= 1; m >>= 1) lsum += __shfl_xor(lsum, m);
    if (lane == 0) red[w] = lsum;
    __syncthreads();
    float mean = (red[0] + red[1] + red[2] + red[3]) * (1.0f / 1024.f);
    float d0 = t0 - mean, d1 = t1 - mean, d2 = t2 - mean, d3 = t3 - mean;
    float lvar = d0 * d0 + d1 * d1 + d2 * d2 + d3 * d3;
#pragma unroll
    for (int m = 32; m >= 1; m >>= 1) lvar += __shfl_xor(lvar, m);
    if (lane == 0) red[4 + w] = lvar;
    __syncthreads();
    float var = (red[4] + red[5] + red[6] + red[7]) * (1.0f / 1024.f);
    float rstd = rsqrtf(var + 1e-5f);
    float4 gv = reinterpret_cast<const float4*>(g)[tid];
    float4 bv = reinterpret_cast<const float4*>(bta)[tid];
    float4 out;
    out.x = d0 * rstd * gv.x + bv.x;
    out.y = d1 * rstd * gv.y + bv.y;
    out.z = d2 * rstd * gv.z + bv.z;
    out.w = d3 * rstd * gv.w + bv.w;
    reinterpret_cast<float4*>(y + (long)s * 1024)[tid] = out;
}

extern "C" void kernel_launch(void* const* d_in, const int* in_sizes, int n_in,
                              void* d_out, int out_size, void* d_ws, size_t ws_size,
                              hipStream_t stream) {
    const float* x = (const float*)d_in[0];
    const float* node_types = (const float*)d_in[1];
    const float* stoich = (const float*)d_in[2];
    const float* Wq = (const float*)d_in[3];
    const float* bq = (const float*)d_in[4];
    const float* Wk = (const float*)d_in[5];
    const float* bk = (const float*)d_in[6];
    const float* Wv = (const float*)d_in[7];
    const float* bv = (const float*)d_in[8];
    const float* Wo = (const float*)d_in[9];
    const float* bo = (const float*)d_in[10];
    const float* Wn1 = (const float*)d_in[11];
    const float* bn1 = (const float*)d_in[12];
    const float* Wn2 = (const float*)d_in[13];
    const float* bn2 = (const float*)d_in[14];
    const float* ln_g = (const float*)d_in[15];
    const float* ln_b = (const float*)d_in[16];
    const int* ei = (const int*)d_in[17];

    char* ws = (char*)d_ws;
    unsigned short* x_bf = (unsigned short*)(ws);                 // 0..4M
    unsigned short* q_bf = (unsigned short*)(ws + (4l << 20));    // 4..8M  [h][s][hd]
    unsigned short* k_bf = (unsigned short*)(ws + (8l << 20));    // 8..12M [h][s][hd]
    unsigned short* v_bf = (unsigned short*)(ws + (12l << 20));   // 12..16M [h][s][hd]
    unsigned short* w_bf = (unsigned short*)(ws + (16l << 20));   // 16..26M 5 slots
    float* hidden = (float*)(ws + (26l << 20));                   // 26..30M
    float* ntwT = (float*)(ws + (30l << 20));                     // 30M +128KB [h][s]
    float* vsumf = (float*)(ws + (30l << 20) + (128l << 10));     // 4KB
    int* rowcnt = (int*)(ws + (30l << 20) + (192l << 10));        // 8KB
    float* p0arr = (float*)(ws + (30l << 20) + (256l << 10));     // 128KB
    float* vsump = (float*)(ws + (30l << 20) + (384l << 10));     // 32KB
    int* cidx = (int*)(ws + (31l << 20));                         // 31..32M
    float* cval = (float*)(ws + (32l << 20));                     // 32..33M
    int* order = (int*)(ws + (33l << 20));                        // 33..49M (scatter only)
    float* pvals = (float*)(ws + (33l << 20));                    // 33..49M (aliases order)
    unsigned short* pvb = (unsigned short*)(ws + (49l << 20));    // 49..53M bf16 [s][1024]
    float* proj = (float*)(ws + (53l << 20));                     // 53..61M

    float* y_out = (float*)d_out;
    float* attn_out = (float*)d_out + (long)S * D;  // 2097152

    hipMemsetAsync(order, 0, 16l << 20, stream);
    hipMemsetAsync(rowcnt, 0, 8l << 10, stream);
    k_convert_x<<<2048, 256, 0, stream>>>(x, x_bf);
    k_convert_w<<<dim3(1024, 5), 256, 0, stream>>>(Wq, Wk, Wv, Wn1, Wo, w_bf);
    k_scatter_max<<<256, 256, 0, stream>>>(ei, order);
    k_scatter_csr<<<256, 256, 0, stream>>>(ei, stoich, order, rowcnt, cidx, cval);
    k_gemm_qkvh<<<dim3(32, 16, 4), 256, 0, stream>>>(x_bf, w_bf, bq, bk, bv, bn1,
                                                     q_bf, k_bf, v_bf, hidden);
    k_ntw<<<2048, 256, 0, stream>>>(hidden, Wn1, node_types, Wn2, bn2, ntwT);
    k_vsum_part<<<dim3(16, 8), 256, 0, stream>>>(v_bf, vsump);
    k_vsum_merge<<<1, 1024, 0, stream>>>(vsump, vsumf);
    k_sparse<<<8192, 256, 0, stream>>>(q_bf, k_bf, v_bf, ntwT, rowcnt, cidx, cval,
                                       vsumf, p0arr, pvals, pvb);
    k_fill<<<8192, 256, 0, stream>>>(p0arr, pvals, cidx, rowcnt, attn_out);
    k_gemm_out<<<dim3(32, 16), 256, 0, stream>>>(pvb, w_bf + 4l * 1048576, bo, proj);
    k_ln<<<2048, 256, 0, stream>>>(x, proj, ln_g, ln_b, y_out);
}

// Round 6
// 201.554 us; speedup vs baseline: 2.5343x; 1.5812x over previous
//
#include <hip/hip_runtime.h>
#include <hip/hip_bf16.h>

#define S 2048
#define D 1024
#define NH 16
#define HD 64
#define NE 65536
#define DH 512
#define SLOTS 128

typedef __attribute__((ext_vector_type(8))) short short8;
typedef __attribute__((ext_vector_type(4))) float f32x4;

#define MFMA16(a, b, c) __builtin_amdgcn_mfma_f32_16x16x32_bf16(a, b, c, 0, 0, 0)

__device__ __forceinline__ unsigned short f2bf(float f) {
    __hip_bfloat16 h = __float2bfloat16(f);
    return *reinterpret_cast<unsigned short*>(&h);
}
__device__ __forceinline__ float bf2f(unsigned short u) {
    unsigned int x = ((unsigned int)u) << 16;
    return *reinterpret_cast<float*>(&x);
}

// async global->LDS, 16B per lane; LDS dest is wave-uniform base + lane*16
__device__ __forceinline__ void gload16(const unsigned short* g, unsigned short* l) {
    __builtin_amdgcn_global_load_lds(
        (const __attribute__((address_space(1))) unsigned int*)g,
        (__attribute__((address_space(3))) unsigned int*)l, 16, 0, 0);
}

// ---------------- prep: x -> bf16, plus zero the order buffer ----------------
__global__ __launch_bounds__(256) void k_convert_x(const float* __restrict__ x,
                                                   unsigned short* __restrict__ xb,
                                                   int* __restrict__ order) {
    int t = blockIdx.x * 256 + threadIdx.x;
    int i = t * 4;
    const float4 v = *reinterpret_cast<const float4*>(x + i);
    xb[i + 0] = f2bf(v.x);
    xb[i + 1] = f2bf(v.y);
    xb[i + 2] = f2bf(v.z);
    xb[i + 3] = f2bf(v.w);
    int4 z = {0, 0, 0, 0};
    int4* o4 = reinterpret_cast<int4*>(order);
    o4[t * 2] = z;
    o4[t * 2 + 1] = z;
}

// 5 weight slots (2MB bf16 each): 0=Wq 1=Wk 2=Wv 3=Wn1[:, :1024] 4=Wo
// mat==5: pack biasAll[3584] = bq|bk|bv|bn1
__global__ __launch_bounds__(256) void k_convert_w(const float* __restrict__ Wq,
                                                   const float* __restrict__ Wk,
                                                   const float* __restrict__ Wv,
                                                   const float* __restrict__ Wn1,
                                                   const float* __restrict__ Wo,
                                                   const float* __restrict__ bq,
                                                   const float* __restrict__ bk,
                                                   const float* __restrict__ bv,
                                                   const float* __restrict__ bn1,
                                                   unsigned short* __restrict__ wb,
                                                   float* __restrict__ biasAll) {
    int row = blockIdx.x, mat = blockIdx.y, t = threadIdx.x;
    if (mat == 5) {
        if (row < 14) {
            int g = row * 256 + t;
            float v = (g < 1024) ? bq[g]
                    : (g < 2048) ? bk[g - 1024]
                    : (g < 3072) ? bv[g - 2048] : bn1[g - 3072];
            biasAll[g] = v;
        }
        return;
    }
    if (mat == 3 && row >= DH) return;
    const float* src;
    long stride = 1024;
    if (mat == 0) src = Wq;
    else if (mat == 1) src = Wk;
    else if (mat == 2) src = Wv;
    else if (mat == 3) { src = Wn1; stride = 1026; }
    else src = Wo;
    const float* r = src + (long)row * stride;
    unsigned short* o = wb + (long)mat * 1048576 + (long)row * 1024;
#pragma unroll
    for (int j = 0; j < 4; j++) o[t * 4 + j] = f2bf(r[t * 4 + j]);
}

// ---------------- stoich CSR build (numpy last-wins dedup) ----------------
__global__ __launch_bounds__(256) void k_scatter_max(const int* __restrict__ ei,
                                                     int* __restrict__ order,
                                                     int* __restrict__ rowcnt) {
    int e = blockIdx.x * 256 + threadIdx.x;
    if (blockIdx.x < 8) rowcnt[blockIdx.x * 256 + threadIdx.x] = 0;
    int r = ei[e], c = ei[NE + e];
    atomicMax(&order[r * S + c], e + 1);
}

__global__ __launch_bounds__(256) void k_scatter_csr(const int* __restrict__ ei,
                                                     const float* __restrict__ st,
                                                     const int* __restrict__ order,
                                                     int* __restrict__ rowcnt,
                                                     int* __restrict__ cidx,
                                                     float* __restrict__ cval) {
    int e = blockIdx.x * 256 + threadIdx.x;
    int r = ei[e], c = ei[NE + e];
    if (order[r * S + c] == e + 1) {
        int i = atomicAdd(&rowcnt[r], 1);
        if (i < SLOTS) {
            cidx[r * SLOTS + i] = c;
            cval[r * SLOTS + i] = st[e];
        }
    }
}

// ---------------- fused QKV+hidden GEMM: 128x128 tile, LDS-staged ----------------
// C[2048 x 3584] = x_bf @ wbig^T, wbig rows = Wq|Wk|Wv|Wn1[:,:1024] (w_bf slots 0-3).
// Epilogue: n<3072 -> Q/K/V bf16 [h][s][hd]; n>=3072 -> hidden fp32 [s][512].
__global__ __launch_bounds__(256) void k_gemm_fused(const unsigned short* __restrict__ A,
                                                    const unsigned short* __restrict__ Bw,
                                                    const float* __restrict__ biasAll,
                                                    unsigned short* __restrict__ qout,
                                                    unsigned short* __restrict__ kout,
                                                    unsigned short* __restrict__ vout,
                                                    float* __restrict__ hidden) {
    __shared__ unsigned short Als[128 * 64];
    __shared__ unsigned short Bls[128 * 64];
    const int tid = threadIdx.x, w = tid >> 6, lane = tid & 63;
    const int l15 = lane & 15, lhi = lane >> 4;
    const int wr = w >> 1, wc = w & 1;
    const int m0 = blockIdx.x * 128, n0 = blockIdx.y * 128;
    f32x4 acc[4][4] = {};
    for (int kt = 0; kt < 16; kt++) {
        __syncthreads();
#pragma unroll
        for (int i = 0; i < 4; i++) {
            int reg = i * 4 + w;
            int idx = reg * 64 + lane;
            int row = idx >> 3, c8 = (idx & 7) * 8;
            gload16(A + (long)(m0 + row) * 1024 + kt * 64 + c8, Als + reg * 512);
            gload16(Bw + (long)(n0 + row) * 1024 + kt * 64 + c8, Bls + reg * 512);
        }
        asm volatile("s_waitcnt vmcnt(0)");
        __syncthreads();
#pragma unroll
        for (int kk = 0; kk < 2; kk++) {
            short8 a[4], b[4];
#pragma unroll
            for (int mi = 0; mi < 4; mi++)
                a[mi] = *reinterpret_cast<const short8*>(Als + (wr * 64 + mi * 16 + l15) * 64 + kk * 32 + lhi * 8);
#pragma unroll
            for (int ni = 0; ni < 4; ni++)
                b[ni] = *reinterpret_cast<const short8*>(Bls + (wc * 64 + ni * 16 + l15) * 64 + kk * 32 + lhi * 8);
#pragma unroll
            for (int mi = 0; mi < 4; mi++)
#pragma unroll
                for (int ni = 0; ni < 4; ni++)
                    acc[mi][ni] = MFMA16(a[mi], b[ni], acc[mi][ni]);
        }
    }
#pragma unroll
    for (int ni = 0; ni < 4; ni++) {
        int n = n0 + wc * 64 + ni * 16 + l15;
        float bb = biasAll[n];
#pragma unroll
        for (int mi = 0; mi < 4; mi++) {
#pragma unroll
            for (int r = 0; r < 4; r++) {
                int m = m0 + wr * 64 + mi * 16 + lhi * 4 + r;
                float v = acc[mi][ni][r] + bb;
                if (n < 3072) {
                    int z = n >> 10, c = n & 1023;
                    int hh = c >> 6, hd = c & 63;
                    unsigned short* dst = (z == 0) ? qout : ((z == 1) ? kout : vout);
                    dst[(long)hh * S * HD + (long)m * HD + hd] = f2bf(v);
                } else {
                    hidden[(long)m * DH + (n - 3072)] = v;
                }
            }
        }
    }
}

// ---------------- out projection GEMM: 128x128 tile, LDS-staged ----------------
__global__ __launch_bounds__(256) void k_gemm_out(const unsigned short* __restrict__ A,
                                                  const unsigned short* __restrict__ Bw,
                                                  const float* __restrict__ bo,
                                                  float* __restrict__ proj) {
    __shared__ unsigned short Als[128 * 64];
    __shared__ unsigned short Bls[128 * 64];
    const int tid = threadIdx.x, w = tid >> 6, lane = tid & 63;
    const int l15 = lane & 15, lhi = lane >> 4;
    const int wr = w >> 1, wc = w & 1;
    const int m0 = blockIdx.x * 128, n0 = blockIdx.y * 128;
    f32x4 acc[4][4] = {};
    for (int kt = 0; kt < 16; kt++) {
        __syncthreads();
#pragma unroll
        for (int i = 0; i < 4; i++) {
            int reg = i * 4 + w;
            int idx = reg * 64 + lane;
            int row = idx >> 3, c8 = (idx & 7) * 8;
            gload16(A + (long)(m0 + row) * 1024 + kt * 64 + c8, Als + reg * 512);
            gload16(Bw + (long)(n0 + row) * 1024 + kt * 64 + c8, Bls + reg * 512);
        }
        asm volatile("s_waitcnt vmcnt(0)");
        __syncthreads();
#pragma unroll
        for (int kk = 0; kk < 2; kk++) {
            short8 a[4], b[4];
#pragma unroll
            for (int mi = 0; mi < 4; mi++)
                a[mi] = *reinterpret_cast<const short8*>(Als + (wr * 64 + mi * 16 + l15) * 64 + kk * 32 + lhi * 8);
#pragma unroll
            for (int ni = 0; ni < 4; ni++)
                b[ni] = *reinterpret_cast<const short8*>(Bls + (wc * 64 + ni * 16 + l15) * 64 + kk * 32 + lhi * 8);
#pragma unroll
            for (int mi = 0; mi < 4; mi++)
#pragma unroll
                for (int ni = 0; ni < 4; ni++)
                    acc[mi][ni] = MFMA16(a[mi], b[ni], acc[mi][ni]);
        }
    }
#pragma unroll
    for (int ni = 0; ni < 4; ni++) {
        int n = n0 + wc * 64 + ni * 16 + l15;
        float bb = bo[n];
#pragma unroll
        for (int mi = 0; mi < 4; mi++) {
#pragma unroll
            for (int r = 0; r < 4; r++) {
                int m = m0 + wr * 64 + mi * 16 + lhi * 4 + r;
                proj[(long)m * 1024 + n] = acc[mi][ni][r] + bb;
            }
        }
    }
}

// ---------------- node-type MLP tail -> ntwT [h][s] ----------------
__global__ __launch_bounds__(256) void k_ntw(const float* __restrict__ hidden,
                                             const float* __restrict__ Wn1,
                                             const float* __restrict__ nt,
                                             const float* __restrict__ Wn2,
                                             const float* __restrict__ bn2,
                                             float* __restrict__ ntwT) {
    int s = blockIdx.x, tid = threadIdx.x;
    __shared__ float rh[DH];
    __shared__ float part[16][17];
    float nt0 = nt[s * 2 + 0], nt1 = nt[s * 2 + 1];
    for (int j = tid; j < DH; j += 256) {
        float v = hidden[(long)s * DH + j] + nt0 * Wn1[(long)j * 1026 + 1024]
                + nt1 * Wn1[(long)j * 1026 + 1025];
        rh[j] = fmaxf(v, 0.f);
    }
    __syncthreads();
    {
        int hh = tid & 15, ch = tid >> 4;
        float p = 0.f;
#pragma unroll
        for (int j = 0; j < 32; j++) p += rh[ch * 32 + j] * Wn2[hh * DH + ch * 32 + j];
        part[ch][hh] = p;
    }
    __syncthreads();
    if (tid < 16) {
        float l = bn2[tid];
#pragma unroll
        for (int c = 0; c < 16; c++) l += part[c][tid];
        float mx = l;
#pragma unroll
        for (int m = 1; m < 16; m <<= 1) mx = fmaxf(mx, __shfl_xor(mx, m));
        float e = __expf(l - mx);
        float sum = e;
#pragma unroll
        for (int m = 1; m < 16; m <<= 1) sum += __shfl_xor(sum, m);
        ntwT[tid * S + s] = e / sum;
    }
}

// ---------------- V column sums: 128-block partials (merged in k_sparse) ----------------
__global__ __launch_bounds__(256) void k_vsum_part(const unsigned short* __restrict__ vb,
                                                   float* __restrict__ vsump) {
    int h = blockIdx.x, j = blockIdx.y, tid = threadIdx.x;
    int w = tid >> 6, lane = tid & 63;
    __shared__ float p[4][64];
    float acc = 0.f;
    int r0 = j * 256 + w * 64;
    for (int k = 0; k < 64; k++)
        acc += bf2f(vb[((long)h * S + r0 + k) * HD + lane]);
    p[w][lane] = acc;
    __syncthreads();
    if (tid < 64) vsump[(h * 8 + j) * 64 + tid] = p[0][tid] + p[1][tid] + p[2][tid] + p[3][tid];
}

// ---------------- sparse attention compute: one WAVE per (h,q) row ----------------
__global__ __launch_bounds__(256, 8) void k_sparse(const unsigned short* __restrict__ qb,
                                                   const unsigned short* __restrict__ kb,
                                                   const unsigned short* __restrict__ vb,
                                                   const float* __restrict__ ntwT,
                                                   const int* __restrict__ rowcnt,
                                                   const int* __restrict__ cidx,
                                                   const float* __restrict__ cval,
                                                   const float* __restrict__ vsump,
                                                   float* __restrict__ p0arr,
                                                   float* __restrict__ pvals,
                                                   unsigned short* __restrict__ pv_out) {
    __shared__ int c_lds[4][SLOTS];
    __shared__ float pd_lds[4][SLOTS];
    const int tid = threadIdx.x, w = tid >> 6, lane = tid & 63;
    int b = (int)blockIdx.x;
    b = (b & 7) * 1024 + (b >> 3);  // XCD swizzle: 2 heads per XCD (K/V L2-resident)
    const int r = b * 4 + w;
    const int h = r >> 11, q = r & 2047;
    const int i_loc = lane & 15, dpart = lane >> 4;
    const int nnz_raw = rowcnt[q];
    const int nnz = nnz_raw < SLOTS ? nnz_raw : SLOTS;
    const int chunks = (nnz + 15) >> 4;

    float qf[16];
    {
        const unsigned short* qp = qb + ((long)h * S + q) * HD + dpart * 16;
        short8 q0 = *reinterpret_cast<const short8*>(qp);
        short8 q1 = *reinterpret_cast<const short8*>(qp + 8);
#pragma unroll
        for (int j = 0; j < 8; j++) {
            qf[j] = bf2f((unsigned short)q0[j]);
            qf[8 + j] = bf2f((unsigned short)q1[j]);
        }
    }

    float s_reg[8];
    int c_reg[8];
#pragma unroll
    for (int c8 = 0; c8 < 8; c8++) {
        s_reg[c8] = -3.0e38f;
        c_reg[c8] = 0;
        if (c8 < chunks) {
            int i = c8 * 16 + i_loc;
            bool valid = i < nnz;
            int idx = q * SLOTS + (valid ? i : 0);
            int c = cidx[idx];
            float vv = cval[idx];
            const unsigned short* kp = kb + ((long)h * S + c) * HD + dpart * 16;
            short8 k0 = *reinterpret_cast<const short8*>(kp);
            short8 k1 = *reinterpret_cast<const short8*>(kp + 8);
            float dot = 0.f;
#pragma unroll
            for (int j = 0; j < 8; j++) {
                dot += qf[j] * bf2f((unsigned short)k0[j]);
                dot += qf[8 + j] * bf2f((unsigned short)k1[j]);
            }
            dot += __shfl_xor(dot, 16);
            dot += __shfl_xor(dot, 32);
            if (valid) {
                s_reg[c8] = dot * 0.125f * ntwT[(long)h * S + c] * vv;
                c_reg[c8] = c;
            }
        }
    }

    float m = s_reg[0];
#pragma unroll
    for (int c8 = 1; c8 < 8; c8++) m = fmaxf(m, s_reg[c8]);
    m = fmaxf(m, __shfl_xor(m, 1));
    m = fmaxf(m, __shfl_xor(m, 2));
    m = fmaxf(m, __shfl_xor(m, 4));
    m = fmaxf(m, __shfl_xor(m, 8));
    const float gm = fmaxf(m, 0.f);

    float e_reg[8];
    float zs = 0.f;
#pragma unroll
    for (int c8 = 0; c8 < 8; c8++) {
        e_reg[c8] = __expf(s_reg[c8] - gm);
        zs += e_reg[c8];
    }
    zs += __shfl_xor(zs, 1);
    zs += __shfl_xor(zs, 2);
    zs += __shfl_xor(zs, 4);
    zs += __shfl_xor(zs, 8);
    const float e0 = __expf(-gm);
    const float Z = zs + (float)(S - nnz) * e0;
    const float inv = 1.0f / Z;
    const float p0 = e0 * inv;

    if (lane == 0) p0arr[r] = p0;
    if (dpart == 0) {
#pragma unroll
        for (int c8 = 0; c8 < 8; c8++) {
            int i = c8 * 16 + i_loc;
            if (c8 < chunks && i < nnz) {
                float p = e_reg[c8] * inv;
                pvals[(long)r * SLOTS + i] = p;
                c_lds[w][i] = c_reg[c8];
                pd_lds[w][i] = p - p0;
            }
        }
    }
    asm volatile("" ::: "memory");

    float vacc = 0.f;
    for (int i = 0; i < nnz; i++) {
        int c = c_lds[w][i];
        float pd = pd_lds[w][i];
        vacc += pd * bf2f(vb[((long)h * S + c) * HD + lane]);
    }
    float vs = 0.f;
#pragma unroll
    for (int j = 0; j < 8; j++) vs += vsump[(h * 8 + j) * 64 + lane];
    vacc += p0 * vs;
    pv_out[(long)q * D + h * HD + lane] = f2bf(vacc);
}

// ---------------- attn row fill + nz scatter: one WAVE per row, streaming ----------------
__global__ __launch_bounds__(256, 8) void k_fill(const float* __restrict__ p0arr,
                                                 const float* __restrict__ pvals,
                                                 const int* __restrict__ cidx,
                                                 const int* __restrict__ rowcnt,
                                                 float* __restrict__ attn_out) {
    const int tid = threadIdx.x, w = tid >> 6, lane = tid & 63;
    const int r = (int)blockIdx.x * 4 + w;
    const int q = r & 2047;
    const int nnz_raw = rowcnt[q];
    const int nnz = nnz_raw < SLOTS ? nnz_raw : SLOTS;
    const float p0 = p0arr[r];

    int c0 = -1, c1 = -1;
    float v0 = 0.f, v1 = 0.f;
    if (lane < nnz) {
        c0 = cidx[q * SLOTS + lane];
        v0 = pvals[(long)r * SLOTS + lane];
    }
    if (lane + 64 < nnz) {
        c1 = cidx[q * SLOTS + lane + 64];
        v1 = pvals[(long)r * SLOTS + lane + 64];
    }

    float* arow = attn_out + (long)r * S;
    float4* a4 = reinterpret_cast<float4*>(arow) + lane;
    const float4 f4 = {p0, p0, p0, p0};
#pragma unroll
    for (int u = 0; u < 8; u++) a4[u * 64] = f4;
    __threadfence_block();
    if (c0 >= 0) arow[c0] = v0;
    if (c1 >= 0) arow[c1] = v1;
}

// ---------------- residual + LayerNorm ----------------
__global__ __launch_bounds__(256) void k_ln(const float* __restrict__ x,
                                            const float* __restrict__ proj,
                                            const float* __restrict__ g,
                                            const float* __restrict__ bta,
                                            float* __restrict__ y) {
    int s = blockIdx.x, tid = threadIdx.x;
    int w = tid >> 6, lane = tid & 63;
    __shared__ float red[8];
    float4 xv = reinterpret_cast<const float4*>(x + (long)s * 1024)[tid];
    float4 pv = reinterpret_cast<const float4*>(proj + (long)s * 1024)[tid];
    float t0 = xv.x + pv.x, t1 = xv.y + pv.y, t2 = xv.z + pv.z, t3 = xv.w + pv.w;
    float lsum = t0 + t1 + t2 + t3;
#pragma unroll
    for (int m = 32; m >= 1; m >>= 1) lsum += __shfl_xor(lsum, m);
    if (lane == 0) red[w] = lsum;
    __syncthreads();
    float mean = (red[0] + red[1] + red[2] + red[3]) * (1.0f / 1024.f);
    float d0 = t0 - mean, d1 = t1 - mean, d2 = t2 - mean, d3 = t3 - mean;
    float lvar = d0 * d0 + d1 * d1 + d2 * d2 + d3 * d3;
#pragma unroll
    for (int m = 32; m >= 1; m >>= 1) lvar += __shfl_xor(lvar, m);
    if (lane == 0) red[4 + w] = lvar;
    __syncthreads();
    float var = (red[4] + red[5] + red[6] + red[7]) * (1.0f / 1024.f);
    float rstd = rsqrtf(var + 1e-5f);
    float4 gv = reinterpret_cast<const float4*>(g)[tid];
    float4 bv = reinterpret_cast<const float4*>(bta)[tid];
    float4 out;
    out.x = d0 * rstd * gv.x + bv.x;
    out.y = d1 * rstd * gv.y + bv.y;
    out.z = d2 * rstd * gv.z + bv.z;
    out.w = d3 * rstd * gv.w + bv.w;
    reinterpret_cast<float4*>(y + (long)s * 1024)[tid] = out;
}

extern "C" void kernel_launch(void* const* d_in, const int* in_sizes, int n_in,
                              void* d_out, int out_size, void* d_ws, size_t ws_size,
                              hipStream_t stream) {
    const float* x = (const float*)d_in[0];
    const float* node_types = (const float*)d_in[1];
    const float* stoich = (const float*)d_in[2];
    const float* Wq = (const float*)d_in[3];
    const float* bq = (const float*)d_in[4];
    const float* Wk = (const float*)d_in[5];
    const float* bk = (const float*)d_in[6];
    const float* Wv = (const float*)d_in[7];
    const float* bv = (const float*)d_in[8];
    const float* Wo = (const float*)d_in[9];
    const float* bo = (const float*)d_in[10];
    const float* Wn1 = (const float*)d_in[11];
    const float* bn1 = (const float*)d_in[12];
    const float* Wn2 = (const float*)d_in[13];
    const float* bn2 = (const float*)d_in[14];
    const float* ln_g = (const float*)d_in[15];
    const float* ln_b = (const float*)d_in[16];
    const int* ei = (const int*)d_in[17];

    char* ws = (char*)d_ws;
    unsigned short* x_bf = (unsigned short*)(ws);                 // 0..4M
    unsigned short* q_bf = (unsigned short*)(ws + (4l << 20));    // 4..8M  [h][s][hd]
    unsigned short* k_bf = (unsigned short*)(ws + (8l << 20));    // 8..12M [h][s][hd]
    unsigned short* v_bf = (unsigned short*)(ws + (12l << 20));   // 12..16M [h][s][hd]
    unsigned short* w_bf = (unsigned short*)(ws + (16l << 20));   // 16..26M 5 slots
    float* hidden = (float*)(ws + (26l << 20));                   // 26..30M
    float* ntwT = (float*)(ws + (30l << 20));                     // 30M +128KB [h][s]
    int* rowcnt = (int*)(ws + (30l << 20) + (192l << 10));        // 8KB
    float* p0arr = (float*)(ws + (30l << 20) + (256l << 10));     // 128KB
    float* vsump = (float*)(ws + (30l << 20) + (384l << 10));     // 32KB
    float* biasAll = (float*)(ws + (30l << 20) + (448l << 10));   // 14KB
    int* cidx = (int*)(ws + (31l << 20));                         // 31..32M
    float* cval = (float*)(ws + (32l << 20));                     // 32..33M
    int* order = (int*)(ws + (33l << 20));                        // 33..49M (scatter only)
    float* pvals = (float*)(ws + (33l << 20));                    // 33..49M (aliases order)
    unsigned short* pvb = (unsigned short*)(ws + (49l << 20));    // 49..53M bf16 [s][1024]
    float* proj = (float*)(ws + (53l << 20));                     // 53..61M

    float* y_out = (float*)d_out;
    float* attn_out = (float*)d_out + (long)S * D;  // 2097152

    k_convert_x<<<2048, 256, 0, stream>>>(x, x_bf, order);
    k_convert_w<<<dim3(1024, 6), 256, 0, stream>>>(Wq, Wk, Wv, Wn1, Wo,
                                                   bq, bk, bv, bn1, w_bf, biasAll);
    k_scatter_max<<<256, 256, 0, stream>>>(ei, order, rowcnt);
    k_scatter_csr<<<256, 256, 0, stream>>>(ei, stoich, order, rowcnt, cidx, cval);
    k_gemm_fused<<<dim3(16, 28), 256, 0, stream>>>(x_bf, w_bf, biasAll,
                                                   q_bf, k_bf, v_bf, hidden);
    k_ntw<<<2048, 256, 0, stream>>>(hidden, Wn1, node_types, Wn2, bn2, ntwT);
    k_vsum_part<<<dim3(16, 8), 256, 0, stream>>>(v_bf, vsump);
    k_sparse<<<8192, 256, 0, stream>>>(q_bf, k_bf, v_bf, ntwT, rowcnt, cidx, cval,
                                       vsump, p0arr, pvals, pvb);
    k_fill<<<8192, 256, 0, stream>>>(p0arr, pvals, cidx, rowcnt, attn_out);
    k_gemm_out<<<dim3(16, 8), 256, 0, stream>>>(pvb, w_bf + 4l * 1048576, bo, proj);
    k_ln<<<2048, 256, 0, stream>>>(x, proj, ln_g, ln_b, y_out);
}

// Round 7
// 161.253 us; speedup vs baseline: 3.1676x; 1.2499x over previous
//
#include <hip/hip_runtime.h>
#include <hip/hip_bf16.h>

#define S 2048
#define D 1024
#define NH 16
#define HD 64
#define NE 65536
#define DH 512
#define SLOTS 128

typedef __attribute__((ext_vector_type(8))) short short8;
typedef __attribute__((ext_vector_type(4))) float f32x4;

#define MFMA16(a, b, c) __builtin_amdgcn_mfma_f32_16x16x32_bf16(a, b, c, 0, 0, 0)

__device__ __forceinline__ unsigned short f2bf(float f) {
    __hip_bfloat16 h = __float2bfloat16(f);
    return *reinterpret_cast<unsigned short*>(&h);
}
__device__ __forceinline__ float bf2f(unsigned short u) {
    unsigned int x = ((unsigned int)u) << 16;
    return *reinterpret_cast<float*>(&x);
}

// async global->LDS, 16B per lane; LDS dest is wave-uniform base + lane*16
__device__ __forceinline__ void gload16(const unsigned short* g, unsigned short* l) {
    __builtin_amdgcn_global_load_lds(
        (const __attribute__((address_space(1))) unsigned int*)g,
        (__attribute__((address_space(3))) unsigned int*)l, 16, 0, 0);
}

// ---------------- prep: weights->bf16, bias pack, x->bf16, rowcnt zero ----------------
// grid (1024, 8): z=0..4 weight mats, z=5 bias+rowcnt, z=6,7 x rows
__global__ __launch_bounds__(256) void k_prep(const float* __restrict__ x,
                                              const float* __restrict__ Wq,
                                              const float* __restrict__ Wk,
                                              const float* __restrict__ Wv,
                                              const float* __restrict__ Wn1,
                                              const float* __restrict__ Wo,
                                              const float* __restrict__ bq,
                                              const float* __restrict__ bk,
                                              const float* __restrict__ bv,
                                              const float* __restrict__ bn1,
                                              unsigned short* __restrict__ xb,
                                              unsigned short* __restrict__ wb,
                                              float* __restrict__ biasAll,
                                              int* __restrict__ rowcnt) {
    int row = blockIdx.x, z = blockIdx.y, t = threadIdx.x;
    if (z == 5) {
        if (row < 14) {
            int g = row * 256 + t;
            float v = (g < 1024) ? bq[g]
                    : (g < 2048) ? bk[g - 1024]
                    : (g < 3072) ? bv[g - 2048] : bn1[g - 3072];
            biasAll[g] = v;
        } else if (row >= 16 && row < 24) {
            rowcnt[(row - 16) * 256 + t] = 0;
        }
        return;
    }
    if (z >= 6) {
        int s = (z - 6) * 1024 + row;
        const float* r = x + (long)s * 1024;
        unsigned short* o = xb + (long)s * 1024;
#pragma unroll
        for (int j = 0; j < 4; j++) o[t * 4 + j] = f2bf(r[t * 4 + j]);
        return;
    }
    if (z == 3 && row >= DH) return;
    const float* src;
    long stride = 1024;
    if (z == 0) src = Wq;
    else if (z == 1) src = Wk;
    else if (z == 2) src = Wv;
    else if (z == 3) { src = Wn1; stride = 1026; }
    else src = Wo;
    const float* r = src + (long)row * stride;
    unsigned short* o = wb + (long)z * 1048576 + (long)row * 1024;
#pragma unroll
    for (int j = 0; j < 4; j++) o[t * 4 + j] = f2bf(r[t * 4 + j]);
}

// ---------------- stoich CSR build (all edges; dedup later in-wave) ----------------
__global__ __launch_bounds__(256) void k_scatter_csr(const int* __restrict__ ei,
                                                     const float* __restrict__ st,
                                                     int* __restrict__ rowcnt,
                                                     int* __restrict__ cpack,
                                                     float* __restrict__ cval) {
    int e = blockIdx.x * 256 + threadIdx.x;
    int r = ei[e], c = ei[NE + e];
    int i = atomicAdd(&rowcnt[r], 1);
    if (i < SLOTS) {
        cpack[r * SLOTS + i] = ((e + 1) << 11) | c;
        cval[r * SLOTS + i] = st[e];
    }
}

// ---------------- fused QKV+hidden GEMM: 128x128 tile, LDS-staged ----------------
__global__ __launch_bounds__(256) void k_gemm_fused(const unsigned short* __restrict__ A,
                                                    const unsigned short* __restrict__ Bw,
                                                    const float* __restrict__ biasAll,
                                                    unsigned short* __restrict__ qout,
                                                    unsigned short* __restrict__ kout,
                                                    unsigned short* __restrict__ vout,
                                                    float* __restrict__ hidden) {
    __shared__ unsigned short Als[128 * 64];
    __shared__ unsigned short Bls[128 * 64];
    const int tid = threadIdx.x, w = tid >> 6, lane = tid & 63;
    const int l15 = lane & 15, lhi = lane >> 4;
    const int wr = w >> 1, wc = w & 1;
    const int m0 = blockIdx.x * 128, n0 = blockIdx.y * 128;
    f32x4 acc[4][4] = {};
    for (int kt = 0; kt < 16; kt++) {
        __syncthreads();
#pragma unroll
        for (int i = 0; i < 4; i++) {
            int reg = i * 4 + w;
            int idx = reg * 64 + lane;
            int row = idx >> 3, c8 = (idx & 7) * 8;
            gload16(A + (long)(m0 + row) * 1024 + kt * 64 + c8, Als + reg * 512);
            gload16(Bw + (long)(n0 + row) * 1024 + kt * 64 + c8, Bls + reg * 512);
        }
        asm volatile("s_waitcnt vmcnt(0)");
        __syncthreads();
#pragma unroll
        for (int kk = 0; kk < 2; kk++) {
            short8 a[4], b[4];
#pragma unroll
            for (int mi = 0; mi < 4; mi++)
                a[mi] = *reinterpret_cast<const short8*>(Als + (wr * 64 + mi * 16 + l15) * 64 + kk * 32 + lhi * 8);
#pragma unroll
            for (int ni = 0; ni < 4; ni++)
                b[ni] = *reinterpret_cast<const short8*>(Bls + (wc * 64 + ni * 16 + l15) * 64 + kk * 32 + lhi * 8);
#pragma unroll
            for (int mi = 0; mi < 4; mi++)
#pragma unroll
                for (int ni = 0; ni < 4; ni++)
                    acc[mi][ni] = MFMA16(a[mi], b[ni], acc[mi][ni]);
        }
    }
#pragma unroll
    for (int ni = 0; ni < 4; ni++) {
        int n = n0 + wc * 64 + ni * 16 + l15;
        float bb = biasAll[n];
#pragma unroll
        for (int mi = 0; mi < 4; mi++) {
#pragma unroll
            for (int r = 0; r < 4; r++) {
                int m = m0 + wr * 64 + mi * 16 + lhi * 4 + r;
                float v = acc[mi][ni][r] + bb;
                if (n < 3072) {
                    int z = n >> 10, c = n & 1023;
                    int hh = c >> 6, hd = c & 63;
                    unsigned short* dst = (z == 0) ? qout : ((z == 1) ? kout : vout);
                    dst[(long)hh * S * HD + (long)m * HD + hd] = f2bf(v);
                } else {
                    hidden[(long)m * DH + (n - 3072)] = v;
                }
            }
        }
    }
}

// ---------------- out projection GEMM: 128x64 tile (256 blocks) ----------------
__global__ __launch_bounds__(256) void k_gemm_out(const unsigned short* __restrict__ A,
                                                  const unsigned short* __restrict__ Bw,
                                                  const float* __restrict__ bo,
                                                  float* __restrict__ proj) {
    __shared__ unsigned short Als[128 * 64];
    __shared__ unsigned short Bls[64 * 64];
    const int tid = threadIdx.x, w = tid >> 6, lane = tid & 63;
    const int l15 = lane & 15, lhi = lane >> 4;
    const int wr = w >> 1, wc = w & 1;
    const int m0 = blockIdx.x * 128, n0 = blockIdx.y * 64;
    f32x4 acc[4][2] = {};
    for (int kt = 0; kt < 16; kt++) {
        __syncthreads();
#pragma unroll
        for (int i = 0; i < 4; i++) {
            int reg = i * 4 + w;
            int idx = reg * 64 + lane;
            int row = idx >> 3, c8 = (idx & 7) * 8;
            gload16(A + (long)(m0 + row) * 1024 + kt * 64 + c8, Als + reg * 512);
        }
#pragma unroll
        for (int i = 0; i < 2; i++) {
            int reg = i * 4 + w;
            int idx = reg * 64 + lane;
            int row = idx >> 3, c8 = (idx & 7) * 8;
            gload16(Bw + (long)(n0 + row) * 1024 + kt * 64 + c8, Bls + reg * 512);
        }
        asm volatile("s_waitcnt vmcnt(0)");
        __syncthreads();
#pragma unroll
        for (int kk = 0; kk < 2; kk++) {
            short8 a[4], b[2];
#pragma unroll
            for (int mi = 0; mi < 4; mi++)
                a[mi] = *reinterpret_cast<const short8*>(Als + (wr * 64 + mi * 16 + l15) * 64 + kk * 32 + lhi * 8);
#pragma unroll
            for (int ni = 0; ni < 2; ni++)
                b[ni] = *reinterpret_cast<const short8*>(Bls + (wc * 32 + ni * 16 + l15) * 64 + kk * 32 + lhi * 8);
#pragma unroll
            for (int mi = 0; mi < 4; mi++)
#pragma unroll
                for (int ni = 0; ni < 2; ni++)
                    acc[mi][ni] = MFMA16(a[mi], b[ni], acc[mi][ni]);
        }
    }
#pragma unroll
    for (int ni = 0; ni < 2; ni++) {
        int n = n0 + wc * 32 + ni * 16 + l15;
        float bb = bo[n];
#pragma unroll
        for (int mi = 0; mi < 4; mi++) {
#pragma unroll
            for (int r = 0; r < 4; r++) {
                int m = m0 + wr * 64 + mi * 16 + lhi * 4 + r;
                proj[(long)m * 1024 + n] = acc[mi][ni][r] + bb;
            }
        }
    }
}

// ---------------- node-type MLP tail + V column-sum partials ----------------
// grid 2176: blocks 0..2047 = ntw rows; 2048..2175 = vsum partials
__global__ __launch_bounds__(256) void k_ntw(const float* __restrict__ hidden,
                                             const float* __restrict__ Wn1,
                                             const float* __restrict__ nt,
                                             const float* __restrict__ Wn2,
                                             const float* __restrict__ bn2,
                                             const unsigned short* __restrict__ vb,
                                             float* __restrict__ ntwT,
                                             float* __restrict__ vsump) {
    int tid = threadIdx.x;
    if (blockIdx.x >= 2048) {
        int idx = blockIdx.x - 2048;
        int h = idx >> 3, j = idx & 7;
        int w = tid >> 6, lane = tid & 63;
        __shared__ float p[4][64];
        float acc = 0.f;
        int r0 = j * 256 + w * 64;
        for (int k = 0; k < 64; k++)
            acc += bf2f(vb[((long)h * S + r0 + k) * HD + lane]);
        p[w][lane] = acc;
        __syncthreads();
        if (tid < 64) vsump[(h * 8 + j) * 64 + tid] = p[0][tid] + p[1][tid] + p[2][tid] + p[3][tid];
        return;
    }
    int s = blockIdx.x;
    __shared__ float rh[DH];
    __shared__ float part[16][17];
    float nt0 = nt[s * 2 + 0], nt1 = nt[s * 2 + 1];
    for (int j = tid; j < DH; j += 256) {
        float v = hidden[(long)s * DH + j] + nt0 * Wn1[(long)j * 1026 + 1024]
                + nt1 * Wn1[(long)j * 1026 + 1025];
        rh[j] = fmaxf(v, 0.f);
    }
    __syncthreads();
    {
        int hh = tid & 15, ch = tid >> 4;
        float p2 = 0.f;
#pragma unroll
        for (int j = 0; j < 32; j++) p2 += rh[ch * 32 + j] * Wn2[hh * DH + ch * 32 + j];
        part[ch][hh] = p2;
    }
    __syncthreads();
    if (tid < 16) {
        float l = bn2[tid];
#pragma unroll
        for (int c = 0; c < 16; c++) l += part[c][tid];
        float mx = l;
#pragma unroll
        for (int m = 1; m < 16; m <<= 1) mx = fmaxf(mx, __shfl_xor(mx, m));
        float e = __expf(l - mx);
        float sum = e;
#pragma unroll
        for (int m = 1; m < 16; m <<= 1) sum += __shfl_xor(sum, m);
        ntwT[tid * S + s] = e / sum;
    }
}

// ---------------- sparse attention + row fill, one WAVE per (h,q) row ----------------
// CSR contains ALL edges (with dups); dedup in-wave by max packed (eid<<11|c).
__global__ __launch_bounds__(256, 4) void k_sparsefill(const unsigned short* __restrict__ qb,
                                                       const unsigned short* __restrict__ kb,
                                                       const unsigned short* __restrict__ vb,
                                                       const float* __restrict__ ntwT,
                                                       const int* __restrict__ rowcnt,
                                                       const int* __restrict__ cpack,
                                                       const float* __restrict__ cval,
                                                       const float* __restrict__ vsump,
                                                       float* __restrict__ attn_out,
                                                       unsigned short* __restrict__ pv_out) {
    __shared__ int c_lds[4][SLOTS];
    __shared__ float pd_lds[4][SLOTS];
    __shared__ unsigned char alive_lds[4][SLOTS];
    const int tid = threadIdx.x, w = tid >> 6, lane = tid & 63;
    int b = (int)blockIdx.x;
    b = (b & 7) * 1024 + (b >> 3);  // XCD swizzle: 2 heads per XCD (K/V L2-resident)
    const int r = b * 4 + w;
    const int h = r >> 11, q = r & 2047;
    const int i_loc = lane & 15, dpart = lane >> 4;
    const int nnz_raw = rowcnt[q];
    const int nnz = nnz_raw < SLOTS ? nnz_raw : SLOTS;
    const int chunks = (nnz + 15) >> 4;

    // stage packed entries to LDS
    for (int i = lane; i < nnz; i += 64) c_lds[w][i] = cpack[q * SLOTS + i];
    asm volatile("" ::: "memory");

    // dedup: alive iff no entry with same col and larger eid (numpy last-wins)
    int myCnt = 0;
    for (int i = lane; i < nnz; i += 64) {
        int pk = c_lds[w][i];
        bool alive = true;
        for (int j = 0; j < nnz; j++) {
            int pj = c_lds[w][j];
            if ((((pj ^ pk) & 2047) == 0) && pj > pk) alive = false;
        }
        alive_lds[w][i] = alive ? 1 : 0;
        myCnt += alive ? 1 : 0;
    }
#pragma unroll
    for (int off = 1; off < 64; off <<= 1) myCnt += __shfl_xor(myCnt, off);
    const int nnz_alive = myCnt;
    asm volatile("" ::: "memory");

    // q fragment: 16 dims of this dpart's quarter
    float qf[16];
    {
        const unsigned short* qp = qb + ((long)h * S + q) * HD + dpart * 16;
        short8 q0 = *reinterpret_cast<const short8*>(qp);
        short8 q1 = *reinterpret_cast<const short8*>(qp + 8);
#pragma unroll
        for (int j = 0; j < 8; j++) {
            qf[j] = bf2f((unsigned short)q0[j]);
            qf[8 + j] = bf2f((unsigned short)q1[j]);
        }
    }

    float s_reg[8], e_reg[8];
    int c_reg[8];
    int vmask = 0;
#pragma unroll
    for (int c8 = 0; c8 < 8; c8++) {
        s_reg[c8] = -3.0e38f;
        c_reg[c8] = 0;
        if (c8 < chunks) {
            int i = c8 * 16 + i_loc;
            bool inr = i < nnz;
            int ig = inr ? i : 0;
            bool valid = inr && alive_lds[w][ig];
            int c = c_lds[w][ig] & 2047;
            float vv = cval[q * SLOTS + ig];
            const unsigned short* kp = kb + ((long)h * S + c) * HD + dpart * 16;
            short8 k0 = *reinterpret_cast<const short8*>(kp);
            short8 k1 = *reinterpret_cast<const short8*>(kp + 8);
            float dot = 0.f;
#pragma unroll
            for (int j = 0; j < 8; j++) {
                dot += qf[j] * bf2f((unsigned short)k0[j]);
                dot += qf[8 + j] * bf2f((unsigned short)k1[j]);
            }
            dot += __shfl_xor(dot, 16);
            dot += __shfl_xor(dot, 32);
            if (valid) {
                s_reg[c8] = dot * 0.125f * ntwT[(long)h * S + c] * vv;
                c_reg[c8] = c;
                vmask |= 1 << c8;
            }
        }
    }

    float m = s_reg[0];
#pragma unroll
    for (int c8 = 1; c8 < 8; c8++) m = fmaxf(m, s_reg[c8]);
    m = fmaxf(m, __shfl_xor(m, 1));
    m = fmaxf(m, __shfl_xor(m, 2));
    m = fmaxf(m, __shfl_xor(m, 4));
    m = fmaxf(m, __shfl_xor(m, 8));
    const float gm = fmaxf(m, 0.f);

    float zs = 0.f;
#pragma unroll
    for (int c8 = 0; c8 < 8; c8++) {
        e_reg[c8] = __expf(s_reg[c8] - gm);  // dead/-inf -> 0
        zs += e_reg[c8];
    }
    zs += __shfl_xor(zs, 1);
    zs += __shfl_xor(zs, 2);
    zs += __shfl_xor(zs, 4);
    zs += __shfl_xor(zs, 8);
    const float e0 = __expf(-gm);
    const float Z = zs + (float)(S - nnz_alive) * e0;
    const float inv = 1.0f / Z;
    const float p0 = e0 * inv;

    // pd for PV (dead entries -> 0)
    if (dpart == 0) {
#pragma unroll
        for (int c8 = 0; c8 < 8; c8++) {
            int i = c8 * 16 + i_loc;
            if (c8 < chunks && i < nnz)
                pd_lds[w][i] = ((vmask >> c8) & 1) ? e_reg[c8] * inv - p0 : 0.f;
        }
    }
    asm volatile("" ::: "memory");

    // fill attn row with p0, then scatter alive values
    float* arow = attn_out + (long)r * S;
    float4* a4 = reinterpret_cast<float4*>(arow) + lane;
    const float4 f4 = {p0, p0, p0, p0};
#pragma unroll
    for (int u = 0; u < 8; u++) a4[u * 64] = f4;
    __threadfence_block();
    if (dpart == 0) {
#pragma unroll
        for (int c8 = 0; c8 < 8; c8++)
            if ((vmask >> c8) & 1) arow[c_reg[c8]] = e_reg[c8] * inv;
    }

    // PV: lanes = output dim
    float vacc = 0.f;
    for (int i = 0; i < nnz; i++) {
        int c = c_lds[w][i] & 2047;
        float pd = pd_lds[w][i];
        vacc += pd * bf2f(vb[((long)h * S + c) * HD + lane]);
    }
    float vs = 0.f;
#pragma unroll
    for (int j = 0; j < 8; j++) vs += vsump[(h * 8 + j) * 64 + lane];
    vacc += p0 * vs;
    pv_out[(long)q * D + h * HD + lane] = f2bf(vacc);
}

// ---------------- residual + LayerNorm ----------------
__global__ __launch_bounds__(256) void k_ln(const float* __restrict__ x,
                                            const float* __restrict__ proj,
                                            const float* __restrict__ g,
                                            const float* __restrict__ bta,
                                            float* __restrict__ y) {
    int s = blockIdx.x, tid = threadIdx.x;
    int w = tid >> 6, lane = tid & 63;
    __shared__ float red[8];
    float4 xv = reinterpret_cast<const float4*>(x + (long)s * 1024)[tid];
    float4 pv = reinterpret_cast<const float4*>(proj + (long)s * 1024)[tid];
    float t0 = xv.x + pv.x, t1 = xv.y + pv.y, t2 = xv.z + pv.z, t3 = xv.w + pv.w;
    float lsum = t0 + t1 + t2 + t3;
#pragma unroll
    for (int m = 32; m >= 1; m >>= 1) lsum += __shfl_xor(lsum, m);
    if (lane == 0) red[w] = lsum;
    __syncthreads();
    float mean = (red[0] + red[1] + red[2] + red[3]) * (1.0f / 1024.f);
    float d0 = t0 - mean, d1 = t1 - mean, d2 = t2 - mean, d3 = t3 - mean;
    float lvar = d0 * d0 + d1 * d1 + d2 * d2 + d3 * d3;
#pragma unroll
    for (int m = 32; m >= 1; m >>= 1) lvar += __shfl_xor(lvar, m);
    if (lane == 0) red[4 + w] = lvar;
    __syncthreads();
    float var = (red[4] + red[5] + red[6] + red[7]) * (1.0f / 1024.f);
    float rstd = rsqrtf(var + 1e-5f);
    float4 gv = reinterpret_cast<const float4*>(g)[tid];
    float4 bv = reinterpret_cast<const float4*>(bta)[tid];
    float4 out;
    out.x = d0 * rstd * gv.x + bv.x;
    out.y = d1 * rstd * gv.y + bv.y;
    out.z = d2 * rstd * gv.z + bv.z;
    out.w = d3 * rstd * gv.w + bv.w;
    reinterpret_cast<float4*>(y + (long)s * 1024)[tid] = out;
}

extern "C" void kernel_launch(void* const* d_in, const int* in_sizes, int n_in,
                              void* d_out, int out_size, void* d_ws, size_t ws_size,
                              hipStream_t stream) {
    const float* x = (const float*)d_in[0];
    const float* node_types = (const float*)d_in[1];
    const float* stoich = (const float*)d_in[2];
    const float* Wq = (const float*)d_in[3];
    const float* bq = (const float*)d_in[4];
    const float* Wk = (const float*)d_in[5];
    const float* bk = (const float*)d_in[6];
    const float* Wv = (const float*)d_in[7];
    const float* bv = (const float*)d_in[8];
    const float* Wo = (const float*)d_in[9];
    const float* bo = (const float*)d_in[10];
    const float* Wn1 = (const float*)d_in[11];
    const float* bn1 = (const float*)d_in[12];
    const float* Wn2 = (const float*)d_in[13];
    const float* bn2 = (const float*)d_in[14];
    const float* ln_g = (const float*)d_in[15];
    const float* ln_b = (const float*)d_in[16];
    const int* ei = (const int*)d_in[17];

    char* ws = (char*)d_ws;
    unsigned short* x_bf = (unsigned short*)(ws);                 // 0..4M
    unsigned short* q_bf = (unsigned short*)(ws + (4l << 20));    // 4..8M  [h][s][hd]
    unsigned short* k_bf = (unsigned short*)(ws + (8l << 20));    // 8..12M [h][s][hd]
    unsigned short* v_bf = (unsigned short*)(ws + (12l << 20));   // 12..16M [h][s][hd]
    unsigned short* w_bf = (unsigned short*)(ws + (16l << 20));   // 16..26M 5 slots
    float* hidden = (float*)(ws + (26l << 20));                   // 26..30M
    float* ntwT = (float*)(ws + (30l << 20));                     // 30M +128KB [h][s]
    int* rowcnt = (int*)(ws + (30l << 20) + (192l << 10));        // 8KB
    float* vsump = (float*)(ws + (30l << 20) + (384l << 10));     // 32KB
    float* biasAll = (float*)(ws + (30l << 20) + (448l << 10));   // 14KB
    int* cpack = (int*)(ws + (31l << 20));                        // 31..32M
    float* cval = (float*)(ws + (32l << 20));                     // 32..33M
    unsigned short* pvb = (unsigned short*)(ws + (49l << 20));    // 49..53M bf16 [s][1024]
    float* proj = (float*)(ws + (53l << 20));                     // 53..61M

    float* y_out = (float*)d_out;
    float* attn_out = (float*)d_out + (long)S * D;  // 2097152

    k_prep<<<dim3(1024, 8), 256, 0, stream>>>(x, Wq, Wk, Wv, Wn1, Wo,
                                              bq, bk, bv, bn1, x_bf, w_bf,
                                              biasAll, rowcnt);
    k_scatter_csr<<<256, 256, 0, stream>>>(ei, stoich, rowcnt, cpack, cval);
    k_gemm_fused<<<dim3(16, 28), 256, 0, stream>>>(x_bf, w_bf, biasAll,
                                                   q_bf, k_bf, v_bf, hidden);
    k_ntw<<<2176, 256, 0, stream>>>(hidden, Wn1, node_types, Wn2, bn2, v_bf,
                                    ntwT, vsump);
    k_sparsefill<<<8192, 256, 0, stream>>>(q_bf, k_bf, v_bf, ntwT, rowcnt,
                                           cpack, cval, vsump, attn_out, pvb);
    k_gemm_out<<<dim3(16, 16), 256, 0, stream>>>(pvb, w_bf + 4l * 1048576, bo, proj);
    k_ln<<<2048, 256, 0, stream>>>(x, proj, ln_g, ln_b, y_out);
}

// Round 9
// 154.937 us; speedup vs baseline: 3.2967x; 1.0408x over previous
//
#include <hip/hip_runtime.h>
#include <hip/hip_bf16.h>

#define S 2048
#define D 1024
#define NH 16
#define HD 64
#define NE 65536
#define DH 512
#define SLOTS 128

typedef __attribute__((ext_vector_type(8))) short short8;
typedef __attribute__((ext_vector_type(4))) float f32x4;

#define MFMA16(a, b, c) __builtin_amdgcn_mfma_f32_16x16x32_bf16(a, b, c, 0, 0, 0)

__device__ __forceinline__ unsigned short f2bf(float f) {
    __hip_bfloat16 h = __float2bfloat16(f);
    return *reinterpret_cast<unsigned short*>(&h);
}
__device__ __forceinline__ float bf2f(unsigned short u) {
    unsigned int x = ((unsigned int)u) << 16;
    return *reinterpret_cast<float*>(&x);
}

// async global->LDS, 16B per lane; LDS dest is wave-uniform base + lane*16
__device__ __forceinline__ void gload16(const unsigned short* g, unsigned short* l) {
    __builtin_amdgcn_global_load_lds(
        (const __attribute__((address_space(1))) unsigned int*)g,
        (__attribute__((address_space(3))) unsigned int*)l, 16, 0, 0);
}

// ---------------- prep: weights->bf16, bias pack, x->bf16, zero rowcnt+vsumf ----------------
// grid (1024, 8): z=0..4 weight mats, z=5 bias/rowcnt/vsumf, z=6,7 x rows
__global__ __launch_bounds__(256) void k_prep(const float* __restrict__ x,
                                              const float* __restrict__ Wq,
                                              const float* __restrict__ Wk,
                                              const float* __restrict__ Wv,
                                              const float* __restrict__ Wn1,
                                              const float* __restrict__ Wo,
                                              const float* __restrict__ bq,
                                              const float* __restrict__ bk,
                                              const float* __restrict__ bv,
                                              const float* __restrict__ bn1,
                                              unsigned short* __restrict__ xb,
                                              unsigned short* __restrict__ wb,
                                              float* __restrict__ biasAll,
                                              int* __restrict__ rowcnt,
                                              float* __restrict__ vsumf) {
    int row = blockIdx.x, z = blockIdx.y, t = threadIdx.x;
    if (z == 5) {
        if (row < 14) {
            int g = row * 256 + t;
            float v = (g < 1024) ? bq[g]
                    : (g < 2048) ? bk[g - 1024]
                    : (g < 3072) ? bv[g - 2048] : bn1[g - 3072];
            biasAll[g] = v;
        } else if (row >= 16 && row < 24) {
            rowcnt[(row - 16) * 256 + t] = 0;
        } else if (row >= 24 && row < 28) {
            vsumf[(row - 24) * 256 + t] = 0.f;
        }
        return;
    }
    if (z >= 6) {
        int s = (z - 6) * 1024 + row;
        const float* r = x + (long)s * 1024;
        unsigned short* o = xb + (long)s * 1024;
#pragma unroll
        for (int j = 0; j < 4; j++) o[t * 4 + j] = f2bf(r[t * 4 + j]);
        return;
    }
    if (z == 3 && row >= DH) return;
    const float* src;
    long stride = 1024;
    if (z == 0) src = Wq;
    else if (z == 1) src = Wk;
    else if (z == 2) src = Wv;
    else if (z == 3) { src = Wn1; stride = 1026; }
    else src = Wo;
    const float* r = src + (long)row * stride;
    unsigned short* o = wb + (long)z * 1048576 + (long)row * 1024;
#pragma unroll
    for (int j = 0; j < 4; j++) o[t * 4 + j] = f2bf(r[t * 4 + j]);
}

// ---------------- fused QKV+hidden GEMM (+CSR scatter plane, +Vsum epilogue) ----------------
// grid (16, 29): y<28 GEMM tiles; y==28 = edge scatter (independent work hidden
// under the GEMM). V-region epilogue (n in [2048,3072)) accumulates column sums
// (incl. bias) into vsumf via one atomicAdd per column per warp-half.
__global__ __launch_bounds__(256) void k_gemm_fused(const unsigned short* __restrict__ A,
                                                    const unsigned short* __restrict__ Bw,
                                                    const float* __restrict__ biasAll,
                                                    const int* __restrict__ ei,
                                                    const float* __restrict__ st,
                                                    int* __restrict__ rowcnt,
                                                    int* __restrict__ cpack,
                                                    float* __restrict__ cval,
                                                    float* __restrict__ vsumf,
                                                    unsigned short* __restrict__ qout,
                                                    unsigned short* __restrict__ kout,
                                                    unsigned short* __restrict__ vout,
                                                    float* __restrict__ hidden) {
    if (blockIdx.y == 28) {
        int base = blockIdx.x * 4096 + threadIdx.x;
#pragma unroll
        for (int k = 0; k < 16; k++) {
            int e = base + k * 256;
            int r = ei[e], c = ei[NE + e];
            int i = atomicAdd(&rowcnt[r], 1);
            if (i < SLOTS) {
                cpack[r * SLOTS + i] = ((e + 1) << 11) | c;
                cval[r * SLOTS + i] = st[e];
            }
        }
        return;
    }
    __shared__ unsigned short Als[128 * 64];
    __shared__ unsigned short Bls[128 * 64];
    const int tid = threadIdx.x, w = tid >> 6, lane = tid & 63;
    const int l15 = lane & 15, lhi = lane >> 4;
    const int wr = w >> 1, wc = w & 1;
    const int m0 = blockIdx.x * 128, n0 = blockIdx.y * 128;
    f32x4 acc[4][4] = {};
    for (int kt = 0; kt < 16; kt++) {
        __syncthreads();
#pragma unroll
        for (int i = 0; i < 4; i++) {
            int reg = i * 4 + w;
            int idx = reg * 64 + lane;
            int row = idx >> 3, c8 = (idx & 7) * 8;
            gload16(A + (long)(m0 + row) * 1024 + kt * 64 + c8, Als + reg * 512);
            gload16(Bw + (long)(n0 + row) * 1024 + kt * 64 + c8, Bls + reg * 512);
        }
        asm volatile("s_waitcnt vmcnt(0)");
        __syncthreads();
#pragma unroll
        for (int kk = 0; kk < 2; kk++) {
            short8 a[4], b[4];
#pragma unroll
            for (int mi = 0; mi < 4; mi++)
                a[mi] = *reinterpret_cast<const short8*>(Als + (wr * 64 + mi * 16 + l15) * 64 + kk * 32 + lhi * 8);
#pragma unroll
            for (int ni = 0; ni < 4; ni++)
                b[ni] = *reinterpret_cast<const short8*>(Bls + (wc * 64 + ni * 16 + l15) * 64 + kk * 32 + lhi * 8);
#pragma unroll
            for (int mi = 0; mi < 4; mi++)
#pragma unroll
                for (int ni = 0; ni < 4; ni++)
                    acc[mi][ni] = MFMA16(a[mi], b[ni], acc[mi][ni]);
        }
    }
#pragma unroll
    for (int ni = 0; ni < 4; ni++) {
        int n = n0 + wc * 64 + ni * 16 + l15;
        float bb = biasAll[n];
        float colsum = 0.f;
#pragma unroll
        for (int mi = 0; mi < 4; mi++) {
#pragma unroll
            for (int r = 0; r < 4; r++) {
                int m = m0 + wr * 64 + mi * 16 + lhi * 4 + r;
                float v = acc[mi][ni][r] + bb;
                colsum += v;
                if (n < 3072) {
                    int z = n >> 10, c = n & 1023;
                    int hh = c >> 6, hd = c & 63;
                    unsigned short* dst = (z == 0) ? qout : ((z == 1) ? kout : vout);
                    dst[(long)hh * S * HD + (long)m * HD + hd] = f2bf(v);
                } else {
                    hidden[(long)m * DH + (n - 3072)] = v;
                }
            }
        }
        if (n >= 2048 && n < 3072) {  // V region: column sums for p0*Vsum
            colsum += __shfl_xor(colsum, 16);
            colsum += __shfl_xor(colsum, 32);
            if (lhi == 0) atomicAdd(&vsumf[n - 2048], colsum);
        }
    }
}

// ---------------- out projection GEMM: 128x64 tile (256 blocks) ----------------
__global__ __launch_bounds__(256) void k_gemm_out(const unsigned short* __restrict__ A,
                                                  const unsigned short* __restrict__ Bw,
                                                  const float* __restrict__ bo,
                                                  float* __restrict__ proj) {
    __shared__ unsigned short Als[128 * 64];
    __shared__ unsigned short Bls[64 * 64];
    const int tid = threadIdx.x, w = tid >> 6, lane = tid & 63;
    const int l15 = lane & 15, lhi = lane >> 4;
    const int wr = w >> 1, wc = w & 1;
    const int m0 = blockIdx.x * 128, n0 = blockIdx.y * 64;
    f32x4 acc[4][2] = {};
    for (int kt = 0; kt < 16; kt++) {
        __syncthreads();
#pragma unroll
        for (int i = 0; i < 4; i++) {
            int reg = i * 4 + w;
            int idx = reg * 64 + lane;
            int row = idx >> 3, c8 = (idx & 7) * 8;
            gload16(A + (long)(m0 + row) * 1024 + kt * 64 + c8, Als + reg * 512);
        }
#pragma unroll
        for (int i = 0; i < 2; i++) {
            int reg = i * 4 + w;
            int idx = reg * 64 + lane;
            int row = idx >> 3, c8 = (idx & 7) * 8;
            gload16(Bw + (long)(n0 + row) * 1024 + kt * 64 + c8, Bls + reg * 512);
        }
        asm volatile("s_waitcnt vmcnt(0)");
        __syncthreads();
#pragma unroll
        for (int kk = 0; kk < 2; kk++) {
            short8 a[4], b[2];
#pragma unroll
            for (int mi = 0; mi < 4; mi++)
                a[mi] = *reinterpret_cast<const short8*>(Als + (wr * 64 + mi * 16 + l15) * 64 + kk * 32 + lhi * 8);
#pragma unroll
            for (int ni = 0; ni < 2; ni++)
                b[ni] = *reinterpret_cast<const short8*>(Bls + (wc * 32 + ni * 16 + l15) * 64 + kk * 32 + lhi * 8);
#pragma unroll
            for (int mi = 0; mi < 4; mi++)
#pragma unroll
                for (int ni = 0; ni < 2; ni++)
                    acc[mi][ni] = MFMA16(a[mi], b[ni], acc[mi][ni]);
        }
    }
#pragma unroll
    for (int ni = 0; ni < 2; ni++) {
        int n = n0 + wc * 32 + ni * 16 + l15;
        float bb = bo[n];
#pragma unroll
        for (int mi = 0; mi < 4; mi++) {
#pragma unroll
            for (int r = 0; r < 4; r++) {
                int m = m0 + wr * 64 + mi * 16 + lhi * 4 + r;
                proj[(long)m * 1024 + n] = acc[mi][ni][r] + bb;
            }
        }
    }
}

// ---------------- node-type MLP tail -> ntwT [h][s] ----------------
__global__ __launch_bounds__(256) void k_ntw(const float* __restrict__ hidden,
                                             const float* __restrict__ Wn1,
                                             const float* __restrict__ nt,
                                             const float* __restrict__ Wn2,
                                             const float* __restrict__ bn2,
                                             float* __restrict__ ntwT) {
    int tid = threadIdx.x;
    int s = blockIdx.x;
    __shared__ float rh[DH];
    __shared__ float part[16][17];
    float nt0 = nt[s * 2 + 0], nt1 = nt[s * 2 + 1];
    for (int j = tid; j < DH; j += 256) {
        float v = hidden[(long)s * DH + j] + nt0 * Wn1[(long)j * 1026 + 1024]
                + nt1 * Wn1[(long)j * 1026 + 1025];
        rh[j] = fmaxf(v, 0.f);
    }
    __syncthreads();
    {
        int hh = tid & 15, ch = tid >> 4;
        float p2 = 0.f;
#pragma unroll
        for (int j = 0; j < 32; j++) p2 += rh[ch * 32 + j] * Wn2[hh * DH + ch * 32 + j];
        part[ch][hh] = p2;
    }
    __syncthreads();
    if (tid < 16) {
        float l = bn2[tid];
#pragma unroll
        for (int c = 0; c < 16; c++) l += part[c][tid];
        float mx = l;
#pragma unroll
        for (int m = 1; m < 16; m <<= 1) mx = fmaxf(mx, __shfl_xor(mx, m));
        float e = __expf(l - mx);
        float sum = e;
#pragma unroll
        for (int m = 1; m < 16; m <<= 1) sum += __shfl_xor(sum, m);
        ntwT[tid * S + s] = e / sum;
    }
}

// ---------------- sparse attention + row fill, one WAVE per (h,q) row ----------------
// CSR contains ALL edges (with dups); dedup in-wave by max packed (eid<<11|c).
__global__ __launch_bounds__(256, 4) void k_sparsefill(const unsigned short* __restrict__ qb,
                                                       const unsigned short* __restrict__ kb,
                                                       const unsigned short* __restrict__ vb,
                                                       const float* __restrict__ ntwT,
                                                       const int* __restrict__ rowcnt,
                                                       const int* __restrict__ cpack,
                                                       const float* __restrict__ cval,
                                                       const float* __restrict__ vsumf,
                                                       float* __restrict__ attn_out,
                                                       unsigned short* __restrict__ pv_out) {
    __shared__ int c_lds[4][SLOTS];
    __shared__ float pd_lds[4][SLOTS];
    __shared__ unsigned char alive_lds[4][SLOTS];
    const int tid = threadIdx.x, w = tid >> 6, lane = tid & 63;
    int b = (int)blockIdx.x;
    b = (b & 7) * 1024 + (b >> 3);  // XCD swizzle: 2 heads per XCD (K/V L2-resident)
    const int r = b * 4 + w;
    const int h = r >> 11, q = r & 2047;
    const int i_loc = lane & 15, dpart = lane >> 4;
    const int nnz_raw = rowcnt[q];
    const int nnz = nnz_raw < SLOTS ? nnz_raw : SLOTS;
    const int chunks = (nnz + 15) >> 4;

    // stage packed entries to LDS
    for (int i = lane; i < nnz; i += 64) c_lds[w][i] = cpack[q * SLOTS + i];
    asm volatile("" ::: "memory");

    // dedup: alive iff no entry with same col and larger eid (numpy last-wins)
    int myCnt = 0;
    for (int i = lane; i < nnz; i += 64) {
        int pk = c_lds[w][i];
        bool alive = true;
        for (int j = 0; j < nnz; j++) {
            int pj = c_lds[w][j];
            if ((((pj ^ pk) & 2047) == 0) && pj > pk) alive = false;
        }
        alive_lds[w][i] = alive ? 1 : 0;
        myCnt += alive ? 1 : 0;
    }
#pragma unroll
    for (int off = 1; off < 64; off <<= 1) myCnt += __shfl_xor(myCnt, off);
    const int nnz_alive = myCnt;
    asm volatile("" ::: "memory");

    // q fragment: 16 dims of this dpart's quarter
    float qf[16];
    {
        const unsigned short* qp = qb + ((long)h * S + q) * HD + dpart * 16;
        short8 q0 = *reinterpret_cast<const short8*>(qp);
        short8 q1 = *reinterpret_cast<const short8*>(qp + 8);
#pragma unroll
        for (int j = 0; j < 8; j++) {
            qf[j] = bf2f((unsigned short)q0[j]);
            qf[8 + j] = bf2f((unsigned short)q1[j]);
        }
    }

    float s_reg[8], e_reg[8];
    int c_reg[8];
    int vmask = 0;
#pragma unroll
    for (int c8 = 0; c8 < 8; c8++) {
        s_reg[c8] = -3.0e38f;
        c_reg[c8] = 0;
        if (c8 < chunks) {
            int i = c8 * 16 + i_loc;
            bool inr = i < nnz;
            int ig = inr ? i : 0;
            bool valid = inr && alive_lds[w][ig];
            int c = c_lds[w][ig] & 2047;
            float vv = cval[q * SLOTS + ig];
            const unsigned short* kp = kb + ((long)h * S + c) * HD + dpart * 16;
            short8 k0 = *reinterpret_cast<const short8*>(kp);
            short8 k1 = *reinterpret_cast<const short8*>(kp + 8);
            float dot = 0.f;
#pragma unroll
            for (int j = 0; j < 8; j++) {
                dot += qf[j] * bf2f((unsigned short)k0[j]);
                dot += qf[8 + j] * bf2f((unsigned short)k1[j]);
            }
            dot += __shfl_xor(dot, 16);
            dot += __shfl_xor(dot, 32);
            if (valid) {
                s_reg[c8] = dot * 0.125f * ntwT[(long)h * S + c] * vv;
                c_reg[c8] = c;
                vmask |= 1 << c8;
            }
        }
    }

    float m = s_reg[0];
#pragma unroll
    for (int c8 = 1; c8 < 8; c8++) m = fmaxf(m, s_reg[c8]);
    m = fmaxf(m, __shfl_xor(m, 1));
    m = fmaxf(m, __shfl_xor(m, 2));
    m = fmaxf(m, __shfl_xor(m, 4));
    m = fmaxf(m, __shfl_xor(m, 8));
    const float gm = fmaxf(m, 0.f);

    float zs = 0.f;
#pragma unroll
    for (int c8 = 0; c8 < 8; c8++) {
        e_reg[c8] = __expf(s_reg[c8] - gm);  // dead/-inf -> 0
        zs += e_reg[c8];
    }
    zs += __shfl_xor(zs, 1);
    zs += __shfl_xor(zs, 2);
    zs += __shfl_xor(zs, 4);
    zs += __shfl_xor(zs, 8);
    const float e0 = __expf(-gm);
    const float Z = zs + (float)(S - nnz_alive) * e0;
    const float inv = 1.0f / Z;
    const float p0 = e0 * inv;

    // pd for PV (dead entries -> 0)
    if (dpart == 0) {
#pragma unroll
        for (int c8 = 0; c8 < 8; c8++) {
            int i = c8 * 16 + i_loc;
            if (c8 < chunks && i < nnz)
                pd_lds[w][i] = ((vmask >> c8) & 1) ? e_reg[c8] * inv - p0 : 0.f;
        }
    }
    asm volatile("" ::: "memory");

    // fill attn row with p0 (non-temporal streaming), then scatter alive values
    float* arow = attn_out + (long)r * S;
    f32x4* a4 = reinterpret_cast<f32x4*>(arow) + lane;
    const f32x4 f4 = {p0, p0, p0, p0};
#pragma unroll
    for (int u = 0; u < 8; u++) __builtin_nontemporal_store(f4, a4 + u * 64);
    __threadfence_block();
    if (dpart == 0) {
#pragma unroll
        for (int c8 = 0; c8 < 8; c8++)
            if ((vmask >> c8) & 1) arow[c_reg[c8]] = e_reg[c8] * inv;
    }

    // PV: lanes = output dim
    float vacc = 0.f;
    for (int i = 0; i < nnz; i++) {
        int c = c_lds[w][i] & 2047;
        float pd = pd_lds[w][i];
        vacc += pd * bf2f(vb[((long)h * S + c) * HD + lane]);
    }
    vacc += p0 * vsumf[h * HD + lane];
    pv_out[(long)q * D + h * HD + lane] = f2bf(vacc);
}

// ---------------- residual + LayerNorm ----------------
__global__ __launch_bounds__(256) void k_ln(const float* __restrict__ x,
                                            const float* __restrict__ proj,
                                            const float* __restrict__ g,
                                            const float* __restrict__ bta,
                                            float* __restrict__ y) {
    int s = blockIdx.x, tid = threadIdx.x;
    int w = tid >> 6, lane = tid & 63;
    __shared__ float red[8];
    float4 xv = reinterpret_cast<const float4*>(x + (long)s * 1024)[tid];
    float4 pv = reinterpret_cast<const float4*>(proj + (long)s * 1024)[tid];
    float t0 = xv.x + pv.x, t1 = xv.y + pv.y, t2 = xv.z + pv.z, t3 = xv.w + pv.w;
    float lsum = t0 + t1 + t2 + t3;
#pragma unroll
    for (int m = 32; m >= 1; m >>= 1) lsum += __shfl_xor(lsum, m);
    if (lane == 0) red[w] = lsum;
    __syncthreads();
    float mean = (red[0] + red[1] + red[2] + red[3]) * (1.0f / 1024.f);
    float d0 = t0 - mean, d1 = t1 - mean, d2 = t2 - mean, d3 = t3 - mean;
    float lvar = d0 * d0 + d1 * d1 + d2 * d2 + d3 * d3;
#pragma unroll
    for (int m = 32; m >= 1; m >>= 1) lvar += __shfl_xor(lvar, m);
    if (lane == 0) red[4 + w] = lvar;
    __syncthreads();
    float var = (red[4] + red[5] + red[6] + red[7]) * (1.0f / 1024.f);
    float rstd = rsqrtf(var + 1e-5f);
    float4 gv = reinterpret_cast<const float4*>(g)[tid];
    float4 bv = reinterpret_cast<const float4*>(bta)[tid];
    float4 out;
    out.x = d0 * rstd * gv.x + bv.x;
    out.y = d1 * rstd * gv.y + bv.y;
    out.z = d2 * rstd * gv.z + bv.z;
    out.w = d3 * rstd * gv.w + bv.w;
    reinterpret_cast<float4*>(y + (long)s * 1024)[tid] = out;
}

extern "C" void kernel_launch(void* const* d_in, const int* in_sizes, int n_in,
                              void* d_out, int out_size, void* d_ws, size_t ws_size,
                              hipStream_t stream) {
    const float* x = (const float*)d_in[0];
    const float* node_types = (const float*)d_in[1];
    const float* stoich = (const float*)d_in[2];
    const float* Wq = (const float*)d_in[3];
    const float* bq = (const float*)d_in[4];
    const float* Wk = (const float*)d_in[5];
    const float* bk = (const float*)d_in[6];
    const float* Wv = (const float*)d_in[7];
    const float* bv = (const float*)d_in[8];
    const float* Wo = (const float*)d_in[9];
    const float* bo = (const float*)d_in[10];
    const float* Wn1 = (const float*)d_in[11];
    const float* bn1 = (const float*)d_in[12];
    const float* Wn2 = (const float*)d_in[13];
    const float* bn2 = (const float*)d_in[14];
    const float* ln_g = (const float*)d_in[15];
    const float* ln_b = (const float*)d_in[16];
    const int* ei = (const int*)d_in[17];

    char* ws = (char*)d_ws;
    unsigned short* x_bf = (unsigned short*)(ws);                 // 0..4M
    unsigned short* q_bf = (unsigned short*)(ws + (4l << 20));    // 4..8M  [h][s][hd]
    unsigned short* k_bf = (unsigned short*)(ws + (8l << 20));    // 8..12M [h][s][hd]
    unsigned short* v_bf = (unsigned short*)(ws + (12l << 20));   // 12..16M [h][s][hd]
    unsigned short* w_bf = (unsigned short*)(ws + (16l << 20));   // 16..26M 5 slots
    float* hidden = (float*)(ws + (26l << 20));                   // 26..30M
    float* ntwT = (float*)(ws + (30l << 20));                     // 30M +128KB [h][s]
    int* rowcnt = (int*)(ws + (30l << 20) + (192l << 10));        // 8KB
    float* vsumf = (float*)(ws + (30l << 20) + (384l << 10));     // 4KB
    float* biasAll = (float*)(ws + (30l << 20) + (448l << 10));   // 14KB
    int* cpack = (int*)(ws + (31l << 20));                        // 31..32M
    float* cval = (float*)(ws + (32l << 20));                     // 32..33M
    unsigned short* pvb = (unsigned short*)(ws + (49l << 20));    // 49..53M bf16 [s][1024]
    float* proj = (float*)(ws + (53l << 20));                     // 53..61M

    float* y_out = (float*)d_out;
    float* attn_out = (float*)d_out + (long)S * D;  // 2097152

    k_prep<<<dim3(1024, 8), 256, 0, stream>>>(x, Wq, Wk, Wv, Wn1, Wo,
                                              bq, bk, bv, bn1, x_bf, w_bf,
                                              biasAll, rowcnt, vsumf);
    k_gemm_fused<<<dim3(16, 29), 256, 0, stream>>>(x_bf, w_bf, biasAll,
                                                   ei, stoich, rowcnt, cpack, cval,
                                                   vsumf, q_bf, k_bf, v_bf, hidden);
    k_ntw<<<2048, 256, 0, stream>>>(hidden, Wn1, node_types, Wn2, bn2, ntwT);
    k_sparsefill<<<8192, 256, 0, stream>>>(q_bf, k_bf, v_bf, ntwT, rowcnt,
                                           cpack, cval, vsumf, attn_out, pvb);
    k_gemm_out<<<dim3(16, 16), 256, 0, stream>>>(pvb, w_bf + 4l * 1048576, bo, proj);
    k_ln<<<2048, 256, 0, stream>>>(x, proj, ln_g, ln_b, y_out);
}